// Round 8
// baseline (6956.139 us; speedup 1.0000x reference)
//
#include <hip/hip_runtime.h>
#include <cstdint>
#include <cstddef>

#define B_ 4
#define N_ 16384
#define S_ 2048
#define K_ 32
#define D_ 64
#define C0_ 67
#define C3_ 256
#define P_ (B_*S_*K_)           // 262144 pixels
#define FEAT_OFF 24576          // B*3*S
#define SEED_OFF (24576 + B_*C3_*S_)

typedef float v2f __attribute__((ext_vector_type(2)));

// ---------------------------------------------------------------------------
// FPS v4: zero global traffic inside the 2048-iteration loop.
// R7 post-mortem: VALU issue halved but time flat => latency-bound. The two
// per-iter global offenders were (a) tid==0's 7 global stores drained by the
// pre-barrier vmcnt(0) wait (~900 cyc), (b) the dependent centroid reload
// xb[cs] (~300 cyc). Both removed: winner index goes to an LDS history
// (bulk-written after the loop); winner coords are carried through the
// reductions (y,z) and read from the LDS x-array (x).
// Numerics are bit-identical to the R4/R7-verified path:
//   d = fma(dz,dz, fma(dy,dy, dx*dx)); dmin = min(dmin,d)  (packed v_pk_*)
// winner = min global index among dmin == block-max (jnp.argmax first-index).
// ---------------------------------------------------------------------------
__global__ __launch_bounds__(1024, 4) void fps_kernel(
    const float* __restrict__ xyz, const int* __restrict__ seed_inds,
    const int* __restrict__ fps_start,
    int* __restrict__ fps_idx, float* __restrict__ new_xyz,
    float* __restrict__ d_out)
{
  const int b = blockIdx.x;
  const int tid = threadIdx.x;
  const int lane = tid & 63;
  const int wid = tid >> 6;          // 0..15
  const float* __restrict__ xb = xyz + (size_t)b * 3 * N_;
  __shared__ v2f s_x[8 * 1024];      // 64 KB: x pairs; flat float view = xb[j]
  __shared__ float s_v[16];
  __shared__ int   s_i[16];
  __shared__ float s_y[16], s_z[16];
  __shared__ int   s_hist[S_];       // 8 KB winner history
  const float* s_xf = (const float*)s_x;
  v2f y2[8], z2[8], dm2[8];
#pragma unroll
  for (int p = 0; p < 8; ++p) {
    int j = p * 2048 + 2 * tid;
    s_x[p * 1024 + tid] = *(const v2f*)&xb[j];
    y2[p] = *(const v2f*)&xb[N_ + j];
    z2[p] = *(const v2f*)&xb[2 * N_ + j];
    dm2[p].x = 1e10f; dm2[p].y = 1e10f;
  }
  int cur = fps_start[b];
  float wx = xb[cur], wy = xb[N_ + cur], wz = xb[2 * N_ + cur]; // once
  __syncthreads();

  for (int it = 0; it < S_; ++it) {
    if (tid == 0) s_hist[it] = cur;                   // LDS only
    v2f cx2, cy2, cz2;
    cx2.x = wx; cx2.y = wx; cy2.x = wy; cy2.y = wy; cz2.x = wz; cz2.y = wz;
    v2f m2; m2.x = -1e30f; m2.y = -1e30f;
#pragma unroll
    for (int p = 0; p < 8; ++p) {
      v2f x2 = s_x[p * 1024 + tid];
      v2f dx = x2 - cx2;
      v2f dy = y2[p] - cy2;
      v2f dz = z2[p] - cz2;
      v2f d  = __builtin_elementwise_fma(dz, dz,
                 __builtin_elementwise_fma(dy, dy, dx * dx));
      v2f dm = __builtin_elementwise_min(dm2[p], d);
      dm2[p] = dm;
      m2 = __builtin_elementwise_max(m2, dm);
    }
    float mv = fmaxf(m2.x, m2.y);
#pragma unroll
    for (int off = 1; off < 64; off <<= 1)
      mv = fmaxf(mv, __shfl_xor(mv, off, 64));        // wave max
    if (lane == 0) s_v[wid] = mv;
    __syncthreads();                                  // B1
    float vs = s_v[lane & 15];
#pragma unroll
    for (int off = 1; off < 16; off <<= 1)
      vs = fmaxf(vs, __shfl_xor(vs, off, 64));        // block max, all lanes
    // lane-local rescan: min global index among dmin==vs, carry its (y,z)
    int cand = 0x7fffffff; float cyv = 0.f, czv = 0.f;
#pragma unroll
    for (int p = 0; p < 8; ++p) {
      int base = p * 2048 + 2 * tid;
      bool h0 = (dm2[p].x == vs) && (base < cand);
      cand = h0 ? base : cand; cyv = h0 ? y2[p].x : cyv; czv = h0 ? z2[p].x : czv;
      bool h1 = (dm2[p].y == vs) && (base + 1 < cand);
      cand = h1 ? base + 1 : cand; cyv = h1 ? y2[p].y : cyv; czv = h1 ? z2[p].y : czv;
    }
#pragma unroll
    for (int off = 1; off < 64; off <<= 1) {          // wave min-idx + coords
      int   oi = __shfl_xor(cand, off, 64);
      float oy = __shfl_xor(cyv, off, 64);
      float oz = __shfl_xor(czv, off, 64);
      bool t = oi < cand;
      cand = t ? oi : cand; cyv = t ? oy : cyv; czv = t ? oz : czv;
    }
    if (lane == 0) { s_i[wid] = cand; s_y[wid] = cyv; s_z[wid] = czv; }
    __syncthreads();                                  // B2
    int ic = s_i[lane & 15];
    float iy = s_y[lane & 15], iz = s_z[lane & 15];
#pragma unroll
    for (int off = 1; off < 16; off <<= 1) {          // block min-idx + coords
      int   oi = __shfl_xor(ic, off, 64);
      float oy = __shfl_xor(iy, off, 64);
      float oz = __shfl_xor(iz, off, 64);
      bool t = oi < ic;
      ic = t ? oi : ic; iy = t ? oy : iy; iz = t ? oz : iz;
    }
    cur = ic; wy = iy; wz = iz;
    wx = s_xf[cur];                                   // broadcast LDS read
  }

  __syncthreads();
  for (int i = tid; i < S_; i += 1024) {              // bulk output phase
    int idx = s_hist[i];
    float x = s_xf[idx];
    float y = xb[N_ + idx], z = xb[2 * N_ + idx];
    fps_idx[b * S_ + i] = idx;
    new_xyz[(b * S_ + i) * 3 + 0] = x;
    new_xyz[(b * S_ + i) * 3 + 1] = y;
    new_xyz[(b * S_ + i) * 3 + 2] = z;
    d_out[(b * 3 + 0) * S_ + i] = x;
    d_out[(b * 3 + 1) * S_ + i] = y;
    d_out[(b * 3 + 2) * S_ + i] = z;
    d_out[SEED_OFF + b * S_ + i] = (float)seed_inds[(size_t)b * N_ + idx];
  }
}

// ---------------------------------------------------------------------------
// Ball query: one wave per centroid; first K in-ball indices ascending,
// pad with first hit.
// ---------------------------------------------------------------------------
__global__ __launch_bounds__(256) void ballquery_kernel(
    const float* __restrict__ xyz, const float* __restrict__ new_xyz,
    int* __restrict__ idxo)
{
  const int c = blockIdx.x * 4 + (threadIdx.x >> 6);
  const int lane = threadIdx.x & 63;
  const int b = c >> 11;
  const float* __restrict__ xb = xyz + (size_t)b * 3 * N_;
  float cx = new_xyz[c * 3 + 0], cy = new_xyz[c * 3 + 1], cz = new_xyz[c * 3 + 2];
  float css = __fadd_rn(__fadd_rn(__fmul_rn(cx, cx), __fmul_rn(cy, cy)),
                        __fmul_rn(cz, cz));
  const double rr = 0.3 * 0.3;
  int cnt = 0, first = -1;
  for (int base = 0; base < N_; base += 64) {
    int j = base + lane;
    float x = xb[j], y = xb[N_ + j], z = xb[2 * N_ + j];
    float pss = __fadd_rn(__fadd_rn(__fmul_rn(x, x), __fmul_rn(y, y)),
                          __fmul_rn(z, z));
    float dot = __fadd_rn(__fadd_rn(__fmul_rn(cx, x), __fmul_rn(cy, y)),
                          __fmul_rn(cz, z));
    float d = __fadd_rn(__fadd_rn(__fmul_rn(-2.f, dot), css), pss);
    bool in = (double)d <= rr;
    unsigned long long m = __ballot(in);
    if (m) {
      if (first < 0) first = base + (__ffsll((long long)m) - 1);
      int rank = (int)__popcll(m & ((1ull << lane) - 1ull));
      int pos = cnt + rank;
      if (in && pos < K_) idxo[(size_t)c * K_ + pos] = j;
      cnt += (int)__popcll(m);
      if (cnt >= K_) break;
    }
  }
  for (int p = cnt + lane; p < K_; p += 64) idxo[(size_t)c * K_ + p] = first;
}

// ---------------------------------------------------------------------------
// points (B,D,N) -> (B,N,D) (only used when ws_size permits).
// ---------------------------------------------------------------------------
__global__ __launch_bounds__(256) void transpose_pts_kernel(
    const float* __restrict__ pts, float* __restrict__ pts_t)
{
  __shared__ float tile[64][65];
  const int blk = blockIdx.x;
  const int b = blk >> 8;
  const int n0 = (blk & 255) * 64;
  const int tx = threadIdx.x & 63, ty = threadIdx.x >> 6;
#pragma unroll
  for (int r = 0; r < 16; ++r) {
    int d = r * 4 + ty;
    tile[d][tx] = pts[((size_t)b * D_ + d) * N_ + n0 + tx];
  }
  __syncthreads();
#pragma unroll
  for (int r = 0; r < 16; ++r) {
    int nl = r * 4 + ty;
    pts_t[((size_t)b * N_ + n0 + nl) * D_ + tx] = tile[tx][nl];
  }
}

__global__ void transpose_w_kernel(
    const float* __restrict__ W0, const float* __restrict__ W1,
    const float* __restrict__ W2, float* __restrict__ wt0,
    float* __restrict__ wt1, float* __restrict__ wt2)
{
  int i = blockIdx.x * 256 + threadIdx.x;
  if (i < 128 * 67) { int co = i / 67, ci = i % 67; wt0[ci * 128 + co] = W0[i]; }
  int i1 = i - 128 * 67;
  if (i1 >= 0 && i1 < 128 * 128) { int co = i1 >> 7, ci = i1 & 127; wt1[ci * 128 + co] = W1[i1]; }
  int i2 = i1 - 128 * 128;
  if (i2 >= 0 && i2 < 256 * 128) { int co = i2 >> 7, ci = i2 & 127; wt2[ci * 256 + co] = W2[i2]; }
}

// ---------------------------------------------------------------------------
// Shared device helpers for the recompute passes.
// ---------------------------------------------------------------------------
__device__ __forceinline__ void stage_x0(
    int gp0, int tid, const float* __restrict__ xyz,
    const float* __restrict__ pts, const float* __restrict__ pts_t, int use_pt,
    const float* __restrict__ new_xyz, const int* __restrict__ idxo,
    float* __restrict__ bufA)
{
  int pxl = tid >> 2, q = tid & 3;
  int gp = gp0 + pxl;
  int b = gp >> 16;
  int s = (gp >> 5) & (S_ - 1);
  int j = idxo[gp];
  if (use_pt) {
    const float* src = pts_t + ((size_t)b * N_ + j) * 64 + q * 16;
#pragma unroll
    for (int v = 0; v < 4; ++v) {
      float4 f = *(const float4*)(src + v * 4);
      int c = 3 + q * 16 + v * 4;
      bufA[(c + 0) * 72 + pxl] = f.x;
      bufA[(c + 1) * 72 + pxl] = f.y;
      bufA[(c + 2) * 72 + pxl] = f.z;
      bufA[(c + 3) * 72 + pxl] = f.w;
    }
  } else {
    const float* src = pts + ((size_t)b * D_ + q * 16) * N_ + j;
#pragma unroll
    for (int v = 0; v < 16; ++v)
      bufA[(3 + q * 16 + v) * 72 + pxl] = src[(size_t)v * N_];
  }
  if (q == 0) {
    const float* xb = xyz + (size_t)b * 3 * N_;
    int c3 = (b * S_ + s) * 3;
    bufA[0 * 72 + pxl] = xb[j] - new_xyz[c3 + 0];
    bufA[1 * 72 + pxl] = xb[N_ + j] - new_xyz[c3 + 1];
    bufA[2 * 72 + pxl] = xb[2 * N_ + j] - new_xyz[c3 + 2];
  }
}

// 8-cout conv micro-tile: acc[4 px][8 co] += buf[ci][pg*4..] * w[ci][cog*8..]
template<int CIN>
__device__ __forceinline__ void conv8(
    const float* __restrict__ buf, const float* __restrict__ wrow, int pg,
    float acc[4][8])
{
  for (int ci = 0; ci < CIN; ++ci) {
    float4 x4 = *(const float4*)&buf[ci * 72 + pg * 4];
    float4 wa = *(const float4*)&wrow[ci * 128];
    float4 wb = *(const float4*)&wrow[ci * 128 + 4];
    float xr[4] = {x4.x, x4.y, x4.z, x4.w};
    float wv[8] = {wa.x, wa.y, wa.z, wa.w, wb.x, wb.y, wb.z, wb.w};
#pragma unroll
    for (int i = 0; i < 4; ++i)
#pragma unroll
      for (int j = 0; j < 8; ++j) acc[i][j] = fmaf(xr[i], wv[j], acc[i][j]);
  }
}

// ---------------------------------------------------------------------------
// passA: conv0 stats only (no y0 store).
// ---------------------------------------------------------------------------
__global__ __launch_bounds__(256) void passA_kernel(
    const float* __restrict__ xyz, const float* __restrict__ pts,
    const float* __restrict__ pts_t, int use_pt,
    const float* __restrict__ new_xyz, const int* __restrict__ idxo,
    const float* __restrict__ wt0, const float* __restrict__ b0,
    float* __restrict__ gsum, float* __restrict__ gsq)
{
  __shared__ __align__(16) float bufA[C0_ * 72];
  __shared__ float s_sum[4][128], s_sq[4][128];
  const int tid = threadIdx.x;
  const int lane = tid & 63, wid = tid >> 6;
  const int cog = tid & 15, pg = tid >> 4;
  float bias[8];
#pragma unroll
  for (int j = 0; j < 8; ++j) bias[j] = b0[cog * 8 + j];
  float ssum[8], ssq[8];
#pragma unroll
  for (int j = 0; j < 8; ++j) { ssum[j] = 0.f; ssq[j] = 0.f; }

  for (int t = 0; t < 4; ++t) {
    const int gp0 = (blockIdx.x * 4 + t) * 64;
    __syncthreads();
    stage_x0(gp0, tid, xyz, pts, pts_t, use_pt, new_xyz, idxo, bufA);
    __syncthreads();
    float acc[4][8];
#pragma unroll
    for (int i = 0; i < 4; ++i)
#pragma unroll
      for (int j = 0; j < 8; ++j) acc[i][j] = 0.f;
    conv8<C0_>(bufA, wt0 + cog * 8, pg, acc);
#pragma unroll
    for (int i = 0; i < 4; ++i)
#pragma unroll
      for (int j = 0; j < 8; ++j) {
        float y = acc[i][j] + bias[j];
        ssum[j] += y;
        ssq[j] = fmaf(y, y, ssq[j]);
      }
  }
#pragma unroll
  for (int j = 0; j < 8; ++j) {
    float v = ssum[j];
    v += __shfl_xor(v, 16, 64); v += __shfl_xor(v, 32, 64);
    float q = ssq[j];
    q += __shfl_xor(q, 16, 64); q += __shfl_xor(q, 32, 64);
    if (lane < 16) { s_sum[wid][lane * 8 + j] = v; s_sq[wid][lane * 8 + j] = q; }
  }
  __syncthreads();
  if (tid < 128) {
    float v = s_sum[0][tid] + s_sum[1][tid] + s_sum[2][tid] + s_sum[3][tid];
    float q = s_sq[0][tid] + s_sq[1][tid] + s_sq[2][tid] + s_sq[3][tid];
    atomicAdd(&gsum[tid], v);
    atomicAdd(&gsq[tid], q);
  }
}

// ---------------------------------------------------------------------------
// passB: recompute conv0 -> BN0+ReLU -> conv1 stats (no y1 store).
// ---------------------------------------------------------------------------
__global__ __launch_bounds__(256) void passB_kernel(
    const float* __restrict__ xyz, const float* __restrict__ pts,
    const float* __restrict__ pts_t, int use_pt,
    const float* __restrict__ new_xyz, const int* __restrict__ idxo,
    const float* __restrict__ wt0, const float* __restrict__ b0,
    const float* __restrict__ scale0, const float* __restrict__ shift0,
    const float* __restrict__ wt1, const float* __restrict__ b1,
    float* __restrict__ gsum, float* __restrict__ gsq)
{
  __shared__ __align__(16) float bufA[C0_ * 72];
  __shared__ __align__(16) float bufB[128 * 72];
  __shared__ float s_sum[4][128], s_sq[4][128];
  const int tid = threadIdx.x;
  const int lane = tid & 63, wid = tid >> 6;
  const int cog = tid & 15, pg = tid >> 4;
  float bias0[8], bias1[8], sc0[8], sh0[8];
#pragma unroll
  for (int j = 0; j < 8; ++j) {
    bias0[j] = b0[cog * 8 + j];
    bias1[j] = b1[cog * 8 + j];
    sc0[j] = scale0[cog * 8 + j];
    sh0[j] = shift0[cog * 8 + j];
  }
  float ssum[8], ssq[8];
#pragma unroll
  for (int j = 0; j < 8; ++j) { ssum[j] = 0.f; ssq[j] = 0.f; }

  for (int t = 0; t < 4; ++t) {
    const int gp0 = (blockIdx.x * 4 + t) * 64;
    __syncthreads();
    stage_x0(gp0, tid, xyz, pts, pts_t, use_pt, new_xyz, idxo, bufA);
    __syncthreads();
    float acc[4][8];
#pragma unroll
    for (int i = 0; i < 4; ++i)
#pragma unroll
      for (int j = 0; j < 8; ++j) acc[i][j] = 0.f;
    conv8<C0_>(bufA, wt0 + cog * 8, pg, acc);
#pragma unroll
    for (int i = 0; i < 4; ++i)
#pragma unroll
      for (int j = 0; j < 8; ++j) {
        float y = acc[i][j] + bias0[j];
        bufB[(cog * 8 + j) * 72 + pg * 4 + i] = fmaxf(0.f, fmaf(y, sc0[j], sh0[j]));
      }
    __syncthreads();
#pragma unroll
    for (int i = 0; i < 4; ++i)
#pragma unroll
      for (int j = 0; j < 8; ++j) acc[i][j] = 0.f;
    conv8<128>(bufB, wt1 + cog * 8, pg, acc);
#pragma unroll
    for (int i = 0; i < 4; ++i)
#pragma unroll
      for (int j = 0; j < 8; ++j) {
        float y = acc[i][j] + bias1[j];
        ssum[j] += y;
        ssq[j] = fmaf(y, y, ssq[j]);
      }
  }
#pragma unroll
  for (int j = 0; j < 8; ++j) {
    float v = ssum[j];
    v += __shfl_xor(v, 16, 64); v += __shfl_xor(v, 32, 64);
    float q = ssq[j];
    q += __shfl_xor(q, 16, 64); q += __shfl_xor(q, 32, 64);
    if (lane < 16) { s_sum[wid][lane * 8 + j] = v; s_sq[wid][lane * 8 + j] = q; }
  }
  __syncthreads();
  if (tid < 128) {
    float v = s_sum[0][tid] + s_sum[1][tid] + s_sum[2][tid] + s_sum[3][tid];
    float q = s_sq[0][tid] + s_sq[1][tid] + s_sq[2][tid] + s_sq[3][tid];
    atomicAdd(&gsum[tid], v);
    atomicAdd(&gsq[tid], q);
  }
}

// ---------------------------------------------------------------------------
// passC: recompute conv0->BN0->conv1->BN1->conv2; emit per-centroid max/min
// of y2 (BN2+ReLU is monotone affine) + conv2 stats. Never stores y2.
// ---------------------------------------------------------------------------
__global__ __launch_bounds__(256) void passC_kernel(
    const float* __restrict__ xyz, const float* __restrict__ pts,
    const float* __restrict__ pts_t, int use_pt,
    const float* __restrict__ new_xyz, const int* __restrict__ idxo,
    const float* __restrict__ wt0, const float* __restrict__ b0,
    const float* __restrict__ scale0, const float* __restrict__ shift0,
    const float* __restrict__ wt1, const float* __restrict__ b1,
    const float* __restrict__ scale1, const float* __restrict__ shift1,
    const float* __restrict__ wt2, const float* __restrict__ b2,
    float* __restrict__ m2max, float* __restrict__ m2min,
    float* __restrict__ gsum, float* __restrict__ gsq)
{
  __shared__ __align__(16) float bufA[128 * 72];   // x0 (67 rows) then x2 (128 rows)
  __shared__ __align__(16) float bufB[128 * 72];   // x1
  __shared__ float s_m[4 * 256], s_n[4 * 256];
  __shared__ float s_sum[4][256], s_sq[4][256];
  const int tid = threadIdx.x;
  const int lane = tid & 63, wid = tid >> 6;
  const int cog = tid & 15, pg = tid >> 4;
  const int co0 = cog * 16;
  float bias0[8], bias1[8], sc0[8], sh0[8], sc1[8], sh1[8];
#pragma unroll
  for (int j = 0; j < 8; ++j) {
    bias0[j] = b0[cog * 8 + j];
    bias1[j] = b1[cog * 8 + j];
    sc0[j] = scale0[cog * 8 + j];
    sh0[j] = shift0[cog * 8 + j];
    sc1[j] = scale1[cog * 8 + j];
    sh1[j] = shift1[cog * 8 + j];
  }
  float bias2[16];
#pragma unroll
  for (int j = 0; j < 16; ++j) bias2[j] = b2[co0 + j];
  float ssum[16], ssq[16];
#pragma unroll
  for (int j = 0; j < 16; ++j) { ssum[j] = 0.f; ssq[j] = 0.f; }

  for (int t = 0; t < 4; ++t) {
    const int gp0 = (blockIdx.x * 4 + t) * 64;
    __syncthreads();
    stage_x0(gp0, tid, xyz, pts, pts_t, use_pt, new_xyz, idxo, bufA);
    __syncthreads();
    // conv0 -> x1
    {
      float acc[4][8];
#pragma unroll
      for (int i = 0; i < 4; ++i)
#pragma unroll
        for (int j = 0; j < 8; ++j) acc[i][j] = 0.f;
      conv8<C0_>(bufA, wt0 + cog * 8, pg, acc);
#pragma unroll
      for (int i = 0; i < 4; ++i)
#pragma unroll
        for (int j = 0; j < 8; ++j) {
          float y = acc[i][j] + bias0[j];
          bufB[(cog * 8 + j) * 72 + pg * 4 + i] = fmaxf(0.f, fmaf(y, sc0[j], sh0[j]));
        }
    }
    __syncthreads();                 // all conv0 reads of bufA done
    // conv1 -> x2 (into bufA)
    {
      float acc[4][8];
#pragma unroll
      for (int i = 0; i < 4; ++i)
#pragma unroll
        for (int j = 0; j < 8; ++j) acc[i][j] = 0.f;
      conv8<128>(bufB, wt1 + cog * 8, pg, acc);
#pragma unroll
      for (int i = 0; i < 4; ++i)
#pragma unroll
        for (int j = 0; j < 8; ++j) {
          float y = acc[i][j] + bias1[j];
          bufA[(cog * 8 + j) * 72 + pg * 4 + i] = fmaxf(0.f, fmaf(y, sc1[j], sh1[j]));
        }
    }
    __syncthreads();
    // conv2 -> stats + per-centroid max/min
    {
      float acc[4][16];
#pragma unroll
      for (int i = 0; i < 4; ++i)
#pragma unroll
        for (int j = 0; j < 16; ++j) acc[i][j] = 0.f;
      const float* wrow = wt2 + co0;
      for (int ci = 0; ci < 128; ++ci) {
        float4 x4 = *(const float4*)&bufA[ci * 72 + pg * 4];
        float xr[4] = {x4.x, x4.y, x4.z, x4.w};
        float wv[16];
#pragma unroll
        for (int w4 = 0; w4 < 4; ++w4) {
          float4 wf = *(const float4*)&wrow[ci * 256 + w4 * 4];
          wv[w4 * 4 + 0] = wf.x; wv[w4 * 4 + 1] = wf.y;
          wv[w4 * 4 + 2] = wf.z; wv[w4 * 4 + 3] = wf.w;
        }
#pragma unroll
        for (int i = 0; i < 4; ++i)
#pragma unroll
          for (int j = 0; j < 16; ++j) acc[i][j] = fmaf(xr[i], wv[j], acc[i][j]);
      }
      float mx[16], mn[16];
#pragma unroll
      for (int j = 0; j < 16; ++j) { mx[j] = -3.4e38f; mn[j] = 3.4e38f; }
#pragma unroll
      for (int i = 0; i < 4; ++i)
#pragma unroll
        for (int j = 0; j < 16; ++j) {
          float y = acc[i][j] + bias2[j];
          ssum[j] += y;
          ssq[j] = fmaf(y, y, ssq[j]);
          mx[j] = fmaxf(mx[j], y);
          mn[j] = fminf(mn[j], y);
        }
#pragma unroll
      for (int j = 0; j < 16; ++j) {
        float a = mx[j];
        a = fmaxf(a, __shfl_xor(a, 16, 64)); a = fmaxf(a, __shfl_xor(a, 32, 64));
        float c = mn[j];
        c = fminf(c, __shfl_xor(c, 16, 64)); c = fminf(c, __shfl_xor(c, 32, 64));
        if (lane < 16) {
          s_m[wid * 256 + lane * 16 + j] = a;
          s_n[wid * 256 + lane * 16 + j] = c;
        }
      }
      __syncthreads();
      {
        int co = tid;
        size_t bsA = (size_t)(gp0 >> 5);   // global (b*S+s) of first centroid
        m2max[bsA * 256 + co]       = fmaxf(s_m[co], s_m[256 + co]);
        m2max[(bsA + 1) * 256 + co] = fmaxf(s_m[512 + co], s_m[768 + co]);
        m2min[bsA * 256 + co]       = fminf(s_n[co], s_n[256 + co]);
        m2min[(bsA + 1) * 256 + co] = fminf(s_n[512 + co], s_n[768 + co]);
      }
    }
  }
#pragma unroll
  for (int j = 0; j < 16; ++j) {
    float v = ssum[j];
    v += __shfl_xor(v, 16, 64); v += __shfl_xor(v, 32, 64);
    float q = ssq[j];
    q += __shfl_xor(q, 16, 64); q += __shfl_xor(q, 32, 64);
    if (lane < 16) { s_sum[wid][lane * 16 + j] = v; s_sq[wid][lane * 16 + j] = q; }
  }
  __syncthreads();
  {
    int co = tid;
    float v = s_sum[0][co] + s_sum[1][co] + s_sum[2][co] + s_sum[3][co];
    float q = s_sq[0][co] + s_sq[1][co] + s_sq[2][co] + s_sq[3][co];
    atomicAdd(&gsum[co], v);
    atomicAdd(&gsq[co], q);
  }
}

__global__ void stats_kernel(
    const float* __restrict__ gsum, const float* __restrict__ gsq,
    const float* __restrict__ g, const float* __restrict__ be,
    float* __restrict__ scale, float* __restrict__ shift, int C)
{
  int c = threadIdx.x;
  if (c >= C) return;
  const float invP = 1.0f / (float)P_;   // P = 2^18, exact division
  float mean = gsum[c] * invP;
  float var = fmaxf(gsq[c] * invP - mean * mean, 0.f);
  float r = 1.0f / sqrtf(var + 1e-5f);
  float sc = g[c] * r;
  scale[c] = sc;
  shift[c] = be[c] - mean * sc;
}

// feat[b][c][s] = relu(scale2*(scale2>=0 ? max : min) + shift2), transposed.
__global__ __launch_bounds__(256) void final_kernel(
    const float* __restrict__ m2max, const float* __restrict__ m2min,
    const float* __restrict__ scale2, const float* __restrict__ shift2,
    float* __restrict__ d_out)
{
  __shared__ float tmx[64][65], tmn[64][65];
  const int blk = blockIdx.x;
  const int b = blk >> 7;
  const int st = (blk >> 2) & 31;
  const int ct = blk & 3;
  const int s0 = st * 64, c0 = ct * 64;
  const int tx = threadIdx.x & 63, ty = threadIdx.x >> 6;
#pragma unroll
  for (int r = 0; r < 16; ++r) {
    int sl = r * 4 + ty;
    size_t src = ((size_t)(b * S_ + s0 + sl)) * 256 + c0 + tx;
    tmx[sl][tx] = m2max[src];
    tmn[sl][tx] = m2min[src];
  }
  __syncthreads();
#pragma unroll
  for (int r = 0; r < 16; ++r) {
    int cl = r * 4 + ty;
    int c = c0 + cl;
    float sc = scale2[c], sh = shift2[c];
    float m = (sc >= 0.f) ? tmx[tx][cl] : tmn[tx][cl];
    d_out[FEAT_OFF + ((size_t)(b * C3_ + c)) * S_ + s0 + tx] =
        fmaxf(0.f, fmaf(m, sc, sh));
  }
}

// ---------------------------------------------------------------------------
extern "C" void kernel_launch(void* const* d_in, const int* in_sizes, int n_in,
                              void* d_out_v, int out_size, void* d_ws,
                              size_t ws_size, hipStream_t stream)
{
  (void)in_sizes; (void)n_in; (void)out_size;
  const float* xyz = (const float*)d_in[0];
  const float* pts = (const float*)d_in[1];
  const int* seed = (const int*)d_in[2];
  const int* fstart = (const int*)d_in[3];
  const float* W0 = (const float*)d_in[4];
  const float* b0 = (const float*)d_in[5];
  const float* g0 = (const float*)d_in[6];
  const float* be0 = (const float*)d_in[7];
  const float* W1 = (const float*)d_in[8];
  const float* b1 = (const float*)d_in[9];
  const float* g1 = (const float*)d_in[10];
  const float* be1 = (const float*)d_in[11];
  const float* W2 = (const float*)d_in[12];
  const float* b2 = (const float*)d_in[13];
  const float* g2 = (const float*)d_in[14];
  const float* be2 = (const float*)d_in[15];
  float* out = (float*)d_out_v;
  char* ws = (char*)d_ws;

  size_t off = 0;
  auto alloc = [&](size_t bytes) -> void* {
    off = (off + 255) & ~(size_t)255;
    void* p = ws + off;
    off += bytes;
    return p;
  };
  // Compact layout: ~18 MB (+16 MB pts_t only if ws_size allows).
  int*   fps_idx = (int*)alloc((size_t)B_ * S_ * 4);
  float* new_xyz = (float*)alloc((size_t)B_ * S_ * 3 * 4);
  int*   idxo    = (int*)alloc((size_t)B_ * S_ * K_ * 4);
  float* m2max   = (float*)alloc((size_t)B_ * S_ * 256 * 4);
  float* m2min   = (float*)alloc((size_t)B_ * S_ * 256 * 4);
  float* stats   = (float*)alloc(1024 * 4);
  float* scsh    = (float*)alloc(1024 * 4);
  float* wt0     = (float*)alloc((size_t)67 * 128 * 4);
  float* wt1     = (float*)alloc((size_t)128 * 128 * 4);
  float* wt2     = (float*)alloc((size_t)128 * 256 * 4);
  const int use_pt = (ws_size >= (off + (size_t)B_ * N_ * D_ * 4 + (1u << 20))) ? 1 : 0;
  float* pts_t   = use_pt ? (float*)alloc((size_t)B_ * N_ * D_ * 4) : (float*)ws;

  float* gsum0 = stats, *gsq0 = stats + 128;
  float* gsum1 = stats + 256, *gsq1 = stats + 384;
  float* gsum2 = stats + 512, *gsq2 = stats + 768;
  float* scale0 = scsh, *shift0 = scsh + 128;
  float* scale1 = scsh + 256, *shift1 = scsh + 384;
  float* scale2 = scsh + 512, *shift2 = scsh + 768;

  hipMemsetAsync(stats, 0, 1024 * 4, stream);
  transpose_w_kernel<<<226, 256, 0, stream>>>(W0, W1, W2, wt0, wt1, wt2);
  if (use_pt)
    transpose_pts_kernel<<<B_ * 256, 256, 0, stream>>>(pts, pts_t);
  fps_kernel<<<B_, 1024, 0, stream>>>(xyz, seed, fstart, fps_idx, new_xyz, out);
  ballquery_kernel<<<B_ * S_ / 4, 256, 0, stream>>>(xyz, new_xyz, idxo);
  passA_kernel<<<1024, 256, 0, stream>>>(xyz, pts, pts_t, use_pt, new_xyz, idxo,
                                         wt0, b0, gsum0, gsq0);
  stats_kernel<<<1, 128, 0, stream>>>(gsum0, gsq0, g0, be0, scale0, shift0, 128);
  passB_kernel<<<1024, 256, 0, stream>>>(xyz, pts, pts_t, use_pt, new_xyz, idxo,
                                         wt0, b0, scale0, shift0, wt1, b1,
                                         gsum1, gsq1);
  stats_kernel<<<1, 128, 0, stream>>>(gsum1, gsq1, g1, be1, scale1, shift1, 128);
  passC_kernel<<<1024, 256, 0, stream>>>(xyz, pts, pts_t, use_pt, new_xyz, idxo,
                                         wt0, b0, scale0, shift0, wt1, b1,
                                         scale1, shift1, wt2, b2,
                                         m2max, m2min, gsum2, gsq2);
  stats_kernel<<<1, 256, 0, stream>>>(gsum2, gsq2, g2, be2, scale2, shift2, 256);
  final_kernel<<<512, 256, 0, stream>>>(m2max, m2min, scale2, shift2, out);
}

// Round 9
// 5778.088 us; speedup vs baseline: 1.2039x; 1.2039x over previous
//
#include <hip/hip_runtime.h>
#include <cstdint>
#include <cstddef>

#define B_ 4
#define N_ 16384
#define S_ 2048
#define K_ 32
#define D_ 64
#define C0_ 67
#define C3_ 256
#define P_ (B_*S_*K_)           // 262144 pixels
#define FEAT_OFF 24576          // B*3*S
#define SEED_OFF (24576 + B_*C3_*S_)

typedef float v2f __attribute__((ext_vector_type(2)));

// ---------------------------------------------------------------------------
// FPS v5: minimize barrier count and wave count (R8 post-mortem: time tracks
// issue-skew x waves + dependent shuffle stages, not instruction count).
// 512 threads (8 waves, 2/SIMD), 32 pts/thread as 16 float2 pairs.
// x,y in LDS (64+64 KB) for winner lookup; y also in regs for the hot loop;
// z,dmin regs only. ONE fused reduction per iteration:
//   lane: packed value-max -> local first-index rescan (no shuffles)
//   wave: 6-stage lexicographic (val desc, idx asc) carrying (val,idx,z)
//   block: 1 barrier, 3-stage reduce over 8 wave entries (double-buffered).
// Distance chain bit-identical to R4-verified: d=fma(dz,dz,fma(dy,dy,dx*dx));
// dmin=min(dmin,d); winner = first-index argmax (lexicographic == rescan+min).
// ---------------------------------------------------------------------------
__global__ __launch_bounds__(512, 2) void fps_kernel(
    const float* __restrict__ xyz, const int* __restrict__ seed_inds,
    const int* __restrict__ fps_start,
    int* __restrict__ fps_idx, float* __restrict__ new_xyz,
    float* __restrict__ d_out)
{
  const int b = blockIdx.x;
  const int tid = threadIdx.x;
  const int lane = tid & 63;
  const int wid = tid >> 6;          // 0..7
  const float* __restrict__ xb = xyz + (size_t)b * 3 * N_;
  __shared__ v2f s_x[8192];          // 64 KB x pairs
  __shared__ v2f s_y[8192];          // 64 KB y pairs
  __shared__ int s_hist[S_];         // 8 KB winner history
  __shared__ float s_rv[2][8];
  __shared__ int   s_ri[2][8];
  __shared__ float s_rz[2][8];
  const float* s_xf = (const float*)s_x;
  const float* s_yf = (const float*)s_y;
  v2f y2[16], z2[16], dm2[16];
#pragma unroll
  for (int p = 0; p < 16; ++p) {
    int j = p * 1024 + 2 * tid;
    v2f xv = *(const v2f*)&xb[j];
    v2f yv = *(const v2f*)&xb[N_ + j];
    s_x[p * 512 + tid] = xv;
    s_y[p * 512 + tid] = yv;
    y2[p] = yv;
    z2[p] = *(const v2f*)&xb[2 * N_ + j];
    dm2[p].x = 1e10f; dm2[p].y = 1e10f;
  }
  int cur = fps_start[b];
  float wx = xb[cur], wy = xb[N_ + cur], wz = xb[2 * N_ + cur]; // once
  __syncthreads();

  for (int it = 0; it < S_; ++it) {
    if (tid == 0) s_hist[it] = cur;                 // LDS only
    v2f cx2, cy2, cz2;
    cx2.x = wx; cx2.y = wx; cy2.x = wy; cy2.y = wy; cz2.x = wz; cz2.y = wz;
    v2f m2; m2.x = -1e30f; m2.y = -1e30f;
#pragma unroll
    for (int p = 0; p < 16; ++p) {
      v2f x2 = s_x[p * 512 + tid];
      v2f dx = x2 - cx2;
      v2f dy = y2[p] - cy2;
      v2f dz = z2[p] - cz2;
      v2f d  = __builtin_elementwise_fma(dz, dz,
                 __builtin_elementwise_fma(dy, dy, dx * dx));
      v2f dm = __builtin_elementwise_min(dm2[p], d);
      dm2[p] = dm;
      m2 = __builtin_elementwise_max(m2, dm);
    }
    float mv = fmaxf(m2.x, m2.y);
    // lane-local first-index rescan (ascending, strict <, no shuffles)
    int cand = 0x7fffffff; float cz = 0.f;
#pragma unroll
    for (int p = 0; p < 16; ++p) {
      int base = p * 1024 + 2 * tid;
      bool h0 = (dm2[p].x == mv) && (base < cand);
      cand = h0 ? base : cand; cz = h0 ? z2[p].x : cz;
      bool h1 = (dm2[p].y == mv) && (base + 1 < cand);
      cand = h1 ? base + 1 : cand; cz = h1 ? z2[p].y : cz;
    }
    // wave reduce: lexicographic (val desc, idx asc), carry z
#pragma unroll
    for (int off = 1; off < 64; off <<= 1) {
      float ov = __shfl_xor(mv, off, 64);
      int   oi = __shfl_xor(cand, off, 64);
      float oz = __shfl_xor(cz, off, 64);
      bool t = (ov > mv) || (ov == mv && oi < cand);
      mv = t ? ov : mv; cand = t ? oi : cand; cz = t ? oz : cz;
    }
    const int buf = it & 1;
    if (lane == 0) { s_rv[buf][wid] = mv; s_ri[buf][wid] = cand; s_rz[buf][wid] = cz; }
    __syncthreads();                                // the ONLY barrier
    float v8 = s_rv[buf][lane & 7];
    int   i8 = s_ri[buf][lane & 7];
    float z8 = s_rz[buf][lane & 7];
#pragma unroll
    for (int off = 1; off < 8; off <<= 1) {         // block reduce, 3 stages
      float ov = __shfl_xor(v8, off, 64);
      int   oi = __shfl_xor(i8, off, 64);
      float oz = __shfl_xor(z8, off, 64);
      bool t = (ov > v8) || (ov == v8 && oi < i8);
      v8 = t ? ov : v8; i8 = t ? oi : i8; z8 = t ? oz : z8;
    }
    cur = i8; wz = z8;
    wx = s_xf[cur];                                 // broadcast LDS reads
    wy = s_yf[cur];
  }

  __syncthreads();
  for (int i = tid; i < S_; i += 512) {             // bulk output phase
    int idx = s_hist[i];
    float x = s_xf[idx];
    float y = s_yf[idx];
    float z = xb[2 * N_ + idx];
    fps_idx[b * S_ + i] = idx;
    new_xyz[(b * S_ + i) * 3 + 0] = x;
    new_xyz[(b * S_ + i) * 3 + 1] = y;
    new_xyz[(b * S_ + i) * 3 + 2] = z;
    d_out[(b * 3 + 0) * S_ + i] = x;
    d_out[(b * 3 + 1) * S_ + i] = y;
    d_out[(b * 3 + 2) * S_ + i] = z;
    d_out[SEED_OFF + b * S_ + i] = (float)seed_inds[(size_t)b * N_ + idx];
  }
}

// ---------------------------------------------------------------------------
// Ball query: one wave per centroid; first K in-ball indices ascending,
// pad with first hit.
// ---------------------------------------------------------------------------
__global__ __launch_bounds__(256) void ballquery_kernel(
    const float* __restrict__ xyz, const float* __restrict__ new_xyz,
    int* __restrict__ idxo)
{
  const int c = blockIdx.x * 4 + (threadIdx.x >> 6);
  const int lane = threadIdx.x & 63;
  const int b = c >> 11;
  const float* __restrict__ xb = xyz + (size_t)b * 3 * N_;
  float cx = new_xyz[c * 3 + 0], cy = new_xyz[c * 3 + 1], cz = new_xyz[c * 3 + 2];
  float css = __fadd_rn(__fadd_rn(__fmul_rn(cx, cx), __fmul_rn(cy, cy)),
                        __fmul_rn(cz, cz));
  const double rr = 0.3 * 0.3;
  int cnt = 0, first = -1;
  for (int base = 0; base < N_; base += 64) {
    int j = base + lane;
    float x = xb[j], y = xb[N_ + j], z = xb[2 * N_ + j];
    float pss = __fadd_rn(__fadd_rn(__fmul_rn(x, x), __fmul_rn(y, y)),
                          __fmul_rn(z, z));
    float dot = __fadd_rn(__fadd_rn(__fmul_rn(cx, x), __fmul_rn(cy, y)),
                          __fmul_rn(cz, z));
    float d = __fadd_rn(__fadd_rn(__fmul_rn(-2.f, dot), css), pss);
    bool in = (double)d <= rr;
    unsigned long long m = __ballot(in);
    if (m) {
      if (first < 0) first = base + (__ffsll((long long)m) - 1);
      int rank = (int)__popcll(m & ((1ull << lane) - 1ull));
      int pos = cnt + rank;
      if (in && pos < K_) idxo[(size_t)c * K_ + pos] = j;
      cnt += (int)__popcll(m);
      if (cnt >= K_) break;
    }
  }
  for (int p = cnt + lane; p < K_; p += 64) idxo[(size_t)c * K_ + p] = first;
}

// ---------------------------------------------------------------------------
// points (B,D,N) -> (B,N,D) (only used when ws_size permits).
// ---------------------------------------------------------------------------
__global__ __launch_bounds__(256) void transpose_pts_kernel(
    const float* __restrict__ pts, float* __restrict__ pts_t)
{
  __shared__ float tile[64][65];
  const int blk = blockIdx.x;
  const int b = blk >> 8;
  const int n0 = (blk & 255) * 64;
  const int tx = threadIdx.x & 63, ty = threadIdx.x >> 6;
#pragma unroll
  for (int r = 0; r < 16; ++r) {
    int d = r * 4 + ty;
    tile[d][tx] = pts[((size_t)b * D_ + d) * N_ + n0 + tx];
  }
  __syncthreads();
#pragma unroll
  for (int r = 0; r < 16; ++r) {
    int nl = r * 4 + ty;
    pts_t[((size_t)b * N_ + n0 + nl) * D_ + tx] = tile[tx][nl];
  }
}

__global__ void transpose_w_kernel(
    const float* __restrict__ W0, const float* __restrict__ W1,
    const float* __restrict__ W2, float* __restrict__ wt0,
    float* __restrict__ wt1, float* __restrict__ wt2)
{
  int i = blockIdx.x * 256 + threadIdx.x;
  if (i < 128 * 67) { int co = i / 67, ci = i % 67; wt0[ci * 128 + co] = W0[i]; }
  int i1 = i - 128 * 67;
  if (i1 >= 0 && i1 < 128 * 128) { int co = i1 >> 7, ci = i1 & 127; wt1[ci * 128 + co] = W1[i1]; }
  int i2 = i1 - 128 * 128;
  if (i2 >= 0 && i2 < 256 * 128) { int co = i2 >> 7, ci = i2 & 127; wt2[ci * 256 + co] = W2[i2]; }
}

// ---------------------------------------------------------------------------
// Shared device helpers for the recompute passes.
// ---------------------------------------------------------------------------
__device__ __forceinline__ void stage_x0(
    int gp0, int tid, const float* __restrict__ xyz,
    const float* __restrict__ pts, const float* __restrict__ pts_t, int use_pt,
    const float* __restrict__ new_xyz, const int* __restrict__ idxo,
    float* __restrict__ bufA)
{
  int pxl = tid >> 2, q = tid & 3;
  int gp = gp0 + pxl;
  int b = gp >> 16;
  int s = (gp >> 5) & (S_ - 1);
  int j = idxo[gp];
  if (use_pt) {
    const float* src = pts_t + ((size_t)b * N_ + j) * 64 + q * 16;
#pragma unroll
    for (int v = 0; v < 4; ++v) {
      float4 f = *(const float4*)(src + v * 4);
      int c = 3 + q * 16 + v * 4;
      bufA[(c + 0) * 72 + pxl] = f.x;
      bufA[(c + 1) * 72 + pxl] = f.y;
      bufA[(c + 2) * 72 + pxl] = f.z;
      bufA[(c + 3) * 72 + pxl] = f.w;
    }
  } else {
    const float* src = pts + ((size_t)b * D_ + q * 16) * N_ + j;
#pragma unroll
    for (int v = 0; v < 16; ++v)
      bufA[(3 + q * 16 + v) * 72 + pxl] = src[(size_t)v * N_];
  }
  if (q == 0) {
    const float* xb = xyz + (size_t)b * 3 * N_;
    int c3 = (b * S_ + s) * 3;
    bufA[0 * 72 + pxl] = xb[j] - new_xyz[c3 + 0];
    bufA[1 * 72 + pxl] = xb[N_ + j] - new_xyz[c3 + 1];
    bufA[2 * 72 + pxl] = xb[2 * N_ + j] - new_xyz[c3 + 2];
  }
}

// 8-cout conv micro-tile: acc[4 px][8 co] += buf[ci][pg*4..] * w[ci][cog*8..]
template<int CIN>
__device__ __forceinline__ void conv8(
    const float* __restrict__ buf, const float* __restrict__ wrow, int pg,
    float acc[4][8])
{
  for (int ci = 0; ci < CIN; ++ci) {
    float4 x4 = *(const float4*)&buf[ci * 72 + pg * 4];
    float4 wa = *(const float4*)&wrow[ci * 128];
    float4 wb = *(const float4*)&wrow[ci * 128 + 4];
    float xr[4] = {x4.x, x4.y, x4.z, x4.w};
    float wv[8] = {wa.x, wa.y, wa.z, wa.w, wb.x, wb.y, wb.z, wb.w};
#pragma unroll
    for (int i = 0; i < 4; ++i)
#pragma unroll
      for (int j = 0; j < 8; ++j) acc[i][j] = fmaf(xr[i], wv[j], acc[i][j]);
  }
}

// ---------------------------------------------------------------------------
// passA: conv0 stats only (no y0 store).
// ---------------------------------------------------------------------------
__global__ __launch_bounds__(256) void passA_kernel(
    const float* __restrict__ xyz, const float* __restrict__ pts,
    const float* __restrict__ pts_t, int use_pt,
    const float* __restrict__ new_xyz, const int* __restrict__ idxo,
    const float* __restrict__ wt0, const float* __restrict__ b0,
    float* __restrict__ gsum, float* __restrict__ gsq)
{
  __shared__ __align__(16) float bufA[C0_ * 72];
  __shared__ float s_sum[4][128], s_sq[4][128];
  const int tid = threadIdx.x;
  const int lane = tid & 63, wid = tid >> 6;
  const int cog = tid & 15, pg = tid >> 4;
  float bias[8];
#pragma unroll
  for (int j = 0; j < 8; ++j) bias[j] = b0[cog * 8 + j];
  float ssum[8], ssq[8];
#pragma unroll
  for (int j = 0; j < 8; ++j) { ssum[j] = 0.f; ssq[j] = 0.f; }

  for (int t = 0; t < 4; ++t) {
    const int gp0 = (blockIdx.x * 4 + t) * 64;
    __syncthreads();
    stage_x0(gp0, tid, xyz, pts, pts_t, use_pt, new_xyz, idxo, bufA);
    __syncthreads();
    float acc[4][8];
#pragma unroll
    for (int i = 0; i < 4; ++i)
#pragma unroll
      for (int j = 0; j < 8; ++j) acc[i][j] = 0.f;
    conv8<C0_>(bufA, wt0 + cog * 8, pg, acc);
#pragma unroll
    for (int i = 0; i < 4; ++i)
#pragma unroll
      for (int j = 0; j < 8; ++j) {
        float y = acc[i][j] + bias[j];
        ssum[j] += y;
        ssq[j] = fmaf(y, y, ssq[j]);
      }
  }
#pragma unroll
  for (int j = 0; j < 8; ++j) {
    float v = ssum[j];
    v += __shfl_xor(v, 16, 64); v += __shfl_xor(v, 32, 64);
    float q = ssq[j];
    q += __shfl_xor(q, 16, 64); q += __shfl_xor(q, 32, 64);
    if (lane < 16) { s_sum[wid][lane * 8 + j] = v; s_sq[wid][lane * 8 + j] = q; }
  }
  __syncthreads();
  if (tid < 128) {
    float v = s_sum[0][tid] + s_sum[1][tid] + s_sum[2][tid] + s_sum[3][tid];
    float q = s_sq[0][tid] + s_sq[1][tid] + s_sq[2][tid] + s_sq[3][tid];
    atomicAdd(&gsum[tid], v);
    atomicAdd(&gsq[tid], q);
  }
}

// ---------------------------------------------------------------------------
// passB: recompute conv0 -> BN0+ReLU -> conv1 stats (no y1 store).
// ---------------------------------------------------------------------------
__global__ __launch_bounds__(256) void passB_kernel(
    const float* __restrict__ xyz, const float* __restrict__ pts,
    const float* __restrict__ pts_t, int use_pt,
    const float* __restrict__ new_xyz, const int* __restrict__ idxo,
    const float* __restrict__ wt0, const float* __restrict__ b0,
    const float* __restrict__ scale0, const float* __restrict__ shift0,
    const float* __restrict__ wt1, const float* __restrict__ b1,
    float* __restrict__ gsum, float* __restrict__ gsq)
{
  __shared__ __align__(16) float bufA[C0_ * 72];
  __shared__ __align__(16) float bufB[128 * 72];
  __shared__ float s_sum[4][128], s_sq[4][128];
  const int tid = threadIdx.x;
  const int lane = tid & 63, wid = tid >> 6;
  const int cog = tid & 15, pg = tid >> 4;
  float bias0[8], bias1[8], sc0[8], sh0[8];
#pragma unroll
  for (int j = 0; j < 8; ++j) {
    bias0[j] = b0[cog * 8 + j];
    bias1[j] = b1[cog * 8 + j];
    sc0[j] = scale0[cog * 8 + j];
    sh0[j] = shift0[cog * 8 + j];
  }
  float ssum[8], ssq[8];
#pragma unroll
  for (int j = 0; j < 8; ++j) { ssum[j] = 0.f; ssq[j] = 0.f; }

  for (int t = 0; t < 4; ++t) {
    const int gp0 = (blockIdx.x * 4 + t) * 64;
    __syncthreads();
    stage_x0(gp0, tid, xyz, pts, pts_t, use_pt, new_xyz, idxo, bufA);
    __syncthreads();
    float acc[4][8];
#pragma unroll
    for (int i = 0; i < 4; ++i)
#pragma unroll
      for (int j = 0; j < 8; ++j) acc[i][j] = 0.f;
    conv8<C0_>(bufA, wt0 + cog * 8, pg, acc);
#pragma unroll
    for (int i = 0; i < 4; ++i)
#pragma unroll
      for (int j = 0; j < 8; ++j) {
        float y = acc[i][j] + bias0[j];
        bufB[(cog * 8 + j) * 72 + pg * 4 + i] = fmaxf(0.f, fmaf(y, sc0[j], sh0[j]));
      }
    __syncthreads();
#pragma unroll
    for (int i = 0; i < 4; ++i)
#pragma unroll
      for (int j = 0; j < 8; ++j) acc[i][j] = 0.f;
    conv8<128>(bufB, wt1 + cog * 8, pg, acc);
#pragma unroll
    for (int i = 0; i < 4; ++i)
#pragma unroll
      for (int j = 0; j < 8; ++j) {
        float y = acc[i][j] + bias1[j];
        ssum[j] += y;
        ssq[j] = fmaf(y, y, ssq[j]);
      }
  }
#pragma unroll
  for (int j = 0; j < 8; ++j) {
    float v = ssum[j];
    v += __shfl_xor(v, 16, 64); v += __shfl_xor(v, 32, 64);
    float q = ssq[j];
    q += __shfl_xor(q, 16, 64); q += __shfl_xor(q, 32, 64);
    if (lane < 16) { s_sum[wid][lane * 8 + j] = v; s_sq[wid][lane * 8 + j] = q; }
  }
  __syncthreads();
  if (tid < 128) {
    float v = s_sum[0][tid] + s_sum[1][tid] + s_sum[2][tid] + s_sum[3][tid];
    float q = s_sq[0][tid] + s_sq[1][tid] + s_sq[2][tid] + s_sq[3][tid];
    atomicAdd(&gsum[tid], v);
    atomicAdd(&gsq[tid], q);
  }
}

// ---------------------------------------------------------------------------
// passC: recompute conv0->BN0->conv1->BN1->conv2; emit per-centroid max/min
// of y2 (BN2+ReLU is monotone affine) + conv2 stats. Never stores y2.
// ---------------------------------------------------------------------------
__global__ __launch_bounds__(256) void passC_kernel(
    const float* __restrict__ xyz, const float* __restrict__ pts,
    const float* __restrict__ pts_t, int use_pt,
    const float* __restrict__ new_xyz, const int* __restrict__ idxo,
    const float* __restrict__ wt0, const float* __restrict__ b0,
    const float* __restrict__ scale0, const float* __restrict__ shift0,
    const float* __restrict__ wt1, const float* __restrict__ b1,
    const float* __restrict__ scale1, const float* __restrict__ shift1,
    const float* __restrict__ wt2, const float* __restrict__ b2,
    float* __restrict__ m2max, float* __restrict__ m2min,
    float* __restrict__ gsum, float* __restrict__ gsq)
{
  __shared__ __align__(16) float bufA[128 * 72];   // x0 (67 rows) then x2 (128 rows)
  __shared__ __align__(16) float bufB[128 * 72];   // x1
  __shared__ float s_m[4 * 256], s_n[4 * 256];
  __shared__ float s_sum[4][256], s_sq[4][256];
  const int tid = threadIdx.x;
  const int lane = tid & 63, wid = tid >> 6;
  const int cog = tid & 15, pg = tid >> 4;
  const int co0 = cog * 16;
  float bias0[8], bias1[8], sc0[8], sh0[8], sc1[8], sh1[8];
#pragma unroll
  for (int j = 0; j < 8; ++j) {
    bias0[j] = b0[cog * 8 + j];
    bias1[j] = b1[cog * 8 + j];
    sc0[j] = scale0[cog * 8 + j];
    sh0[j] = shift0[cog * 8 + j];
    sc1[j] = scale1[cog * 8 + j];
    sh1[j] = shift1[cog * 8 + j];
  }
  float bias2[16];
#pragma unroll
  for (int j = 0; j < 16; ++j) bias2[j] = b2[co0 + j];
  float ssum[16], ssq[16];
#pragma unroll
  for (int j = 0; j < 16; ++j) { ssum[j] = 0.f; ssq[j] = 0.f; }

  for (int t = 0; t < 4; ++t) {
    const int gp0 = (blockIdx.x * 4 + t) * 64;
    __syncthreads();
    stage_x0(gp0, tid, xyz, pts, pts_t, use_pt, new_xyz, idxo, bufA);
    __syncthreads();
    // conv0 -> x1
    {
      float acc[4][8];
#pragma unroll
      for (int i = 0; i < 4; ++i)
#pragma unroll
        for (int j = 0; j < 8; ++j) acc[i][j] = 0.f;
      conv8<C0_>(bufA, wt0 + cog * 8, pg, acc);
#pragma unroll
      for (int i = 0; i < 4; ++i)
#pragma unroll
        for (int j = 0; j < 8; ++j) {
          float y = acc[i][j] + bias0[j];
          bufB[(cog * 8 + j) * 72 + pg * 4 + i] = fmaxf(0.f, fmaf(y, sc0[j], sh0[j]));
        }
    }
    __syncthreads();                 // all conv0 reads of bufA done
    // conv1 -> x2 (into bufA)
    {
      float acc[4][8];
#pragma unroll
      for (int i = 0; i < 4; ++i)
#pragma unroll
        for (int j = 0; j < 8; ++j) acc[i][j] = 0.f;
      conv8<128>(bufB, wt1 + cog * 8, pg, acc);
#pragma unroll
      for (int i = 0; i < 4; ++i)
#pragma unroll
        for (int j = 0; j < 8; ++j) {
          float y = acc[i][j] + bias1[j];
          bufA[(cog * 8 + j) * 72 + pg * 4 + i] = fmaxf(0.f, fmaf(y, sc1[j], sh1[j]));
        }
    }
    __syncthreads();
    // conv2 -> stats + per-centroid max/min
    {
      float acc[4][16];
#pragma unroll
      for (int i = 0; i < 4; ++i)
#pragma unroll
        for (int j = 0; j < 16; ++j) acc[i][j] = 0.f;
      const float* wrow = wt2 + co0;
      for (int ci = 0; ci < 128; ++ci) {
        float4 x4 = *(const float4*)&bufA[ci * 72 + pg * 4];
        float xr[4] = {x4.x, x4.y, x4.z, x4.w};
        float wv[16];
#pragma unroll
        for (int w4 = 0; w4 < 4; ++w4) {
          float4 wf = *(const float4*)&wrow[ci * 256 + w4 * 4];
          wv[w4 * 4 + 0] = wf.x; wv[w4 * 4 + 1] = wf.y;
          wv[w4 * 4 + 2] = wf.z; wv[w4 * 4 + 3] = wf.w;
        }
#pragma unroll
        for (int i = 0; i < 4; ++i)
#pragma unroll
          for (int j = 0; j < 16; ++j) acc[i][j] = fmaf(xr[i], wv[j], acc[i][j]);
      }
      float mx[16], mn[16];
#pragma unroll
      for (int j = 0; j < 16; ++j) { mx[j] = -3.4e38f; mn[j] = 3.4e38f; }
#pragma unroll
      for (int i = 0; i < 4; ++i)
#pragma unroll
        for (int j = 0; j < 16; ++j) {
          float y = acc[i][j] + bias2[j];
          ssum[j] += y;
          ssq[j] = fmaf(y, y, ssq[j]);
          mx[j] = fmaxf(mx[j], y);
          mn[j] = fminf(mn[j], y);
        }
#pragma unroll
      for (int j = 0; j < 16; ++j) {
        float a = mx[j];
        a = fmaxf(a, __shfl_xor(a, 16, 64)); a = fmaxf(a, __shfl_xor(a, 32, 64));
        float c = mn[j];
        c = fminf(c, __shfl_xor(c, 16, 64)); c = fminf(c, __shfl_xor(c, 32, 64));
        if (lane < 16) {
          s_m[wid * 256 + lane * 16 + j] = a;
          s_n[wid * 256 + lane * 16 + j] = c;
        }
      }
      __syncthreads();
      {
        int co = tid;
        size_t bsA = (size_t)(gp0 >> 5);   // global (b*S+s) of first centroid
        m2max[bsA * 256 + co]       = fmaxf(s_m[co], s_m[256 + co]);
        m2max[(bsA + 1) * 256 + co] = fmaxf(s_m[512 + co], s_m[768 + co]);
        m2min[bsA * 256 + co]       = fminf(s_n[co], s_n[256 + co]);
        m2min[(bsA + 1) * 256 + co] = fminf(s_n[512 + co], s_n[768 + co]);
      }
    }
  }
#pragma unroll
  for (int j = 0; j < 16; ++j) {
    float v = ssum[j];
    v += __shfl_xor(v, 16, 64); v += __shfl_xor(v, 32, 64);
    float q = ssq[j];
    q += __shfl_xor(q, 16, 64); q += __shfl_xor(q, 32, 64);
    if (lane < 16) { s_sum[wid][lane * 16 + j] = v; s_sq[wid][lane * 16 + j] = q; }
  }
  __syncthreads();
  {
    int co = tid;
    float v = s_sum[0][co] + s_sum[1][co] + s_sum[2][co] + s_sum[3][co];
    float q = s_sq[0][co] + s_sq[1][co] + s_sq[2][co] + s_sq[3][co];
    atomicAdd(&gsum[co], v);
    atomicAdd(&gsq[co], q);
  }
}

__global__ void stats_kernel(
    const float* __restrict__ gsum, const float* __restrict__ gsq,
    const float* __restrict__ g, const float* __restrict__ be,
    float* __restrict__ scale, float* __restrict__ shift, int C)
{
  int c = threadIdx.x;
  if (c >= C) return;
  const float invP = 1.0f / (float)P_;   // P = 2^18, exact division
  float mean = gsum[c] * invP;
  float var = fmaxf(gsq[c] * invP - mean * mean, 0.f);
  float r = 1.0f / sqrtf(var + 1e-5f);
  float sc = g[c] * r;
  scale[c] = sc;
  shift[c] = be[c] - mean * sc;
}

// feat[b][c][s] = relu(scale2*(scale2>=0 ? max : min) + shift2), transposed.
__global__ __launch_bounds__(256) void final_kernel(
    const float* __restrict__ m2max, const float* __restrict__ m2min,
    const float* __restrict__ scale2, const float* __restrict__ shift2,
    float* __restrict__ d_out)
{
  __shared__ float tmx[64][65], tmn[64][65];
  const int blk = blockIdx.x;
  const int b = blk >> 7;
  const int st = (blk >> 2) & 31;
  const int ct = blk & 3;
  const int s0 = st * 64, c0 = ct * 64;
  const int tx = threadIdx.x & 63, ty = threadIdx.x >> 6;
#pragma unroll
  for (int r = 0; r < 16; ++r) {
    int sl = r * 4 + ty;
    size_t src = ((size_t)(b * S_ + s0 + sl)) * 256 + c0 + tx;
    tmx[sl][tx] = m2max[src];
    tmn[sl][tx] = m2min[src];
  }
  __syncthreads();
#pragma unroll
  for (int r = 0; r < 16; ++r) {
    int cl = r * 4 + ty;
    int c = c0 + cl;
    float sc = scale2[c], sh = shift2[c];
    float m = (sc >= 0.f) ? tmx[tx][cl] : tmn[tx][cl];
    d_out[FEAT_OFF + ((size_t)(b * C3_ + c)) * S_ + s0 + tx] =
        fmaxf(0.f, fmaf(m, sc, sh));
  }
}

// ---------------------------------------------------------------------------
extern "C" void kernel_launch(void* const* d_in, const int* in_sizes, int n_in,
                              void* d_out_v, int out_size, void* d_ws,
                              size_t ws_size, hipStream_t stream)
{
  (void)in_sizes; (void)n_in; (void)out_size;
  const float* xyz = (const float*)d_in[0];
  const float* pts = (const float*)d_in[1];
  const int* seed = (const int*)d_in[2];
  const int* fstart = (const int*)d_in[3];
  const float* W0 = (const float*)d_in[4];
  const float* b0 = (const float*)d_in[5];
  const float* g0 = (const float*)d_in[6];
  const float* be0 = (const float*)d_in[7];
  const float* W1 = (const float*)d_in[8];
  const float* b1 = (const float*)d_in[9];
  const float* g1 = (const float*)d_in[10];
  const float* be1 = (const float*)d_in[11];
  const float* W2 = (const float*)d_in[12];
  const float* b2 = (const float*)d_in[13];
  const float* g2 = (const float*)d_in[14];
  const float* be2 = (const float*)d_in[15];
  float* out = (float*)d_out_v;
  char* ws = (char*)d_ws;

  size_t off = 0;
  auto alloc = [&](size_t bytes) -> void* {
    off = (off + 255) & ~(size_t)255;
    void* p = ws + off;
    off += bytes;
    return p;
  };
  // Compact layout: ~18 MB (+16 MB pts_t only if ws_size allows).
  int*   fps_idx = (int*)alloc((size_t)B_ * S_ * 4);
  float* new_xyz = (float*)alloc((size_t)B_ * S_ * 3 * 4);
  int*   idxo    = (int*)alloc((size_t)B_ * S_ * K_ * 4);
  float* m2max   = (float*)alloc((size_t)B_ * S_ * 256 * 4);
  float* m2min   = (float*)alloc((size_t)B_ * S_ * 256 * 4);
  float* stats   = (float*)alloc(1024 * 4);
  float* scsh    = (float*)alloc(1024 * 4);
  float* wt0     = (float*)alloc((size_t)67 * 128 * 4);
  float* wt1     = (float*)alloc((size_t)128 * 128 * 4);
  float* wt2     = (float*)alloc((size_t)128 * 256 * 4);
  const int use_pt = (ws_size >= (off + (size_t)B_ * N_ * D_ * 4 + (1u << 20))) ? 1 : 0;
  float* pts_t   = use_pt ? (float*)alloc((size_t)B_ * N_ * D_ * 4) : (float*)ws;

  float* gsum0 = stats, *gsq0 = stats + 128;
  float* gsum1 = stats + 256, *gsq1 = stats + 384;
  float* gsum2 = stats + 512, *gsq2 = stats + 768;
  float* scale0 = scsh, *shift0 = scsh + 128;
  float* scale1 = scsh + 256, *shift1 = scsh + 384;
  float* scale2 = scsh + 512, *shift2 = scsh + 768;

  hipMemsetAsync(stats, 0, 1024 * 4, stream);
  transpose_w_kernel<<<226, 256, 0, stream>>>(W0, W1, W2, wt0, wt1, wt2);
  if (use_pt)
    transpose_pts_kernel<<<B_ * 256, 256, 0, stream>>>(pts, pts_t);
  fps_kernel<<<B_, 512, 0, stream>>>(xyz, seed, fstart, fps_idx, new_xyz, out);
  ballquery_kernel<<<B_ * S_ / 4, 256, 0, stream>>>(xyz, new_xyz, idxo);
  passA_kernel<<<1024, 256, 0, stream>>>(xyz, pts, pts_t, use_pt, new_xyz, idxo,
                                         wt0, b0, gsum0, gsq0);
  stats_kernel<<<1, 128, 0, stream>>>(gsum0, gsq0, g0, be0, scale0, shift0, 128);
  passB_kernel<<<1024, 256, 0, stream>>>(xyz, pts, pts_t, use_pt, new_xyz, idxo,
                                         wt0, b0, scale0, shift0, wt1, b1,
                                         gsum1, gsq1);
  stats_kernel<<<1, 128, 0, stream>>>(gsum1, gsq1, g1, be1, scale1, shift1, 128);
  passC_kernel<<<1024, 256, 0, stream>>>(xyz, pts, pts_t, use_pt, new_xyz, idxo,
                                         wt0, b0, scale0, shift0, wt1, b1,
                                         scale1, shift1, wt2, b2,
                                         m2max, m2min, gsum2, gsq2);
  stats_kernel<<<1, 256, 0, stream>>>(gsum2, gsq2, g2, be2, scale2, shift2, 256);
  final_kernel<<<512, 256, 0, stream>>>(m2max, m2min, scale2, shift2, out);
}

// Round 10
// 5735.271 us; speedup vs baseline: 1.2129x; 1.0075x over previous
//
#include <hip/hip_runtime.h>
#include <cstdint>
#include <cstddef>

#define B_ 4
#define N_ 16384
#define S_ 2048
#define K_ 32
#define D_ 64
#define C0_ 67
#define C3_ 256
#define P_ (B_*S_*K_)           // 262144 pixels
#define FEAT_OFF 24576          // B*3*S
#define SEED_OFF (24576 + B_*C3_*S_)

typedef float v2f __attribute__((ext_vector_type(2)));

// DPP wave-reduce steps (VALU, ~2-4 cyc each; replaces ~120-cyc ds_permute).
// update_dpp(old=own, src=own, ctrl): invalid lanes keep own value => identity.
#define DPP_FMAX(v, CTRL)                                                     \
  do { int _i = __float_as_int(v);                                            \
       int _o = __builtin_amdgcn_update_dpp(_i, _i, CTRL, 0xf, 0xf, false);   \
       (v) = fmaxf((v), __int_as_float(_o)); } while (0)

#define DPP_IMINZ(gi, zi, CTRL)                                               \
  do { int _oi = __builtin_amdgcn_update_dpp(gi, gi, CTRL, 0xf, 0xf, false);  \
       int _oz = __builtin_amdgcn_update_dpp(zi, zi, CTRL, 0xf, 0xf, false);  \
       bool _t = _oi < (gi);                                                  \
       (gi) = _t ? _oi : (gi); (zi) = _t ? _oz : (zi); } while (0)

// ---------------------------------------------------------------------------
// FPS v6: no ds_permute on the critical path (R9 post-mortem: ~27 dependent
// ~120-cyc swizzles/iter explained the stubborn ~5000 cyc/iter).
// 512 threads, 32 pts/thread as 16 float2 pairs; x,y in LDS; z,dmin in regs.
// Per iteration: packed-VALU body -> 6-step DPP value max -> readlane(63)
// -> lane-local first-index rescan -> 6-step DPP min-index reduce (carries z)
// -> readlane -> ONE barrier -> all-lanes redundant scan of 8 wave entries
// (broadcast LDS reads, no cross-lane) -> (x,y) LDS lookup.
// Numerics bit-identical to R4-verified: d=fma(dz,dz,fma(dy,dy,dx*dx));
// dmin=min(dmin,d); winner = first-index argmax.
// ---------------------------------------------------------------------------
__global__ __launch_bounds__(512, 2) void fps_kernel(
    const float* __restrict__ xyz, const int* __restrict__ seed_inds,
    const int* __restrict__ fps_start,
    int* __restrict__ fps_idx, float* __restrict__ new_xyz,
    float* __restrict__ d_out)
{
  const int b = blockIdx.x;
  const int tid = threadIdx.x;
  const int lane = tid & 63;
  const int wid = tid >> 6;          // 0..7
  const float* __restrict__ xb = xyz + (size_t)b * 3 * N_;
  __shared__ v2f s_x[8192];          // 64 KB x pairs
  __shared__ v2f s_y[8192];          // 64 KB y pairs
  __shared__ int s_hist[S_];         // 8 KB winner history
  __shared__ float s_rv[2][8];
  __shared__ int   s_ri[2][8];
  __shared__ float s_rz[2][8];
  const float* s_xf = (const float*)s_x;
  const float* s_yf = (const float*)s_y;
  v2f y2[16], z2[16], dm2[16];
#pragma unroll
  for (int p = 0; p < 16; ++p) {
    int j = p * 1024 + 2 * tid;
    v2f xv = *(const v2f*)&xb[j];
    v2f yv = *(const v2f*)&xb[N_ + j];
    s_x[p * 512 + tid] = xv;
    s_y[p * 512 + tid] = yv;
    y2[p] = yv;
    z2[p] = *(const v2f*)&xb[2 * N_ + j];
    dm2[p].x = 1e10f; dm2[p].y = 1e10f;
  }
  int cur = fps_start[b];
  float wx = xb[cur], wy = xb[N_ + cur], wz = xb[2 * N_ + cur]; // once
  __syncthreads();

  for (int it = 0; it < S_; ++it) {
    if (tid == 0) s_hist[it] = cur;                 // LDS only
    v2f cx2, cy2, cz2;
    cx2.x = wx; cx2.y = wx; cy2.x = wy; cy2.y = wy; cz2.x = wz; cz2.y = wz;
    v2f m2; m2.x = -1e30f; m2.y = -1e30f;
#pragma unroll
    for (int p = 0; p < 16; ++p) {
      v2f x2 = s_x[p * 512 + tid];
      v2f dx = x2 - cx2;
      v2f dy = y2[p] - cy2;
      v2f dz = z2[p] - cz2;
      v2f d  = __builtin_elementwise_fma(dz, dz,
                 __builtin_elementwise_fma(dy, dy, dx * dx));
      v2f dm = __builtin_elementwise_min(dm2[p], d);
      dm2[p] = dm;
      m2 = __builtin_elementwise_max(m2, dm);
    }
    float wm = fmaxf(m2.x, m2.y);
    // wave value-max via DPP (full max lands in lanes 32-63)
    DPP_FMAX(wm, 0x111); DPP_FMAX(wm, 0x112); DPP_FMAX(wm, 0x114);
    DPP_FMAX(wm, 0x118); DPP_FMAX(wm, 0x142); DPP_FMAX(wm, 0x143);
    const float WM = __int_as_float(
        __builtin_amdgcn_readlane(__float_as_int(wm), 63));
    // lane-local first-index rescan against WM (ascending, strict <)
    int gidx = 0x7fffffff; int zi = 0;
#pragma unroll
    for (int p = 0; p < 16; ++p) {
      int base = p * 1024 + 2 * tid;
      bool h0 = (dm2[p].x == WM) && (base < gidx);
      gidx = h0 ? base : gidx; zi = h0 ? __float_as_int(z2[p].x) : zi;
      bool h1 = (dm2[p].y == WM) && (base + 1 < gidx);
      gidx = h1 ? base + 1 : gidx; zi = h1 ? __float_as_int(z2[p].y) : zi;
    }
    // wave min-index reduce via DPP, carrying z
    DPP_IMINZ(gidx, zi, 0x111); DPP_IMINZ(gidx, zi, 0x112);
    DPP_IMINZ(gidx, zi, 0x114); DPP_IMINZ(gidx, zi, 0x118);
    DPP_IMINZ(gidx, zi, 0x142); DPP_IMINZ(gidx, zi, 0x143);
    const int wi  = __builtin_amdgcn_readlane(gidx, 63);
    const int wzi = __builtin_amdgcn_readlane(zi, 63);
    const int buf = it & 1;
    if (lane == 0) {
      s_rv[buf][wid] = WM; s_ri[buf][wid] = wi; s_rz[buf][wid] = __int_as_float(wzi);
    }
    __syncthreads();                                // the ONLY barrier
    // redundant block reduce: every lane scans 8 entries (broadcast reads)
    float bv = s_rv[buf][0]; int bi = s_ri[buf][0]; float bz = s_rz[buf][0];
#pragma unroll
    for (int w = 1; w < 8; ++w) {
      float vv = s_rv[buf][w]; int iv = s_ri[buf][w]; float zv = s_rz[buf][w];
      bool t = (vv > bv) || (vv == bv && iv < bi);
      bv = t ? vv : bv; bi = t ? iv : bi; bz = t ? zv : bz;
    }
    cur = bi; wz = bz;
    wx = s_xf[cur];                                 // broadcast LDS reads
    wy = s_yf[cur];
  }

  __syncthreads();
  for (int i = tid; i < S_; i += 512) {             // bulk output phase
    int idx = s_hist[i];
    float x = s_xf[idx];
    float y = s_yf[idx];
    float z = xb[2 * N_ + idx];
    fps_idx[b * S_ + i] = idx;
    new_xyz[(b * S_ + i) * 3 + 0] = x;
    new_xyz[(b * S_ + i) * 3 + 1] = y;
    new_xyz[(b * S_ + i) * 3 + 2] = z;
    d_out[(b * 3 + 0) * S_ + i] = x;
    d_out[(b * 3 + 1) * S_ + i] = y;
    d_out[(b * 3 + 2) * S_ + i] = z;
    d_out[SEED_OFF + b * S_ + i] = (float)seed_inds[(size_t)b * N_ + idx];
  }
}

// ---------------------------------------------------------------------------
// Ball query: one wave per centroid; first K in-ball indices ascending,
// pad with first hit.
// ---------------------------------------------------------------------------
__global__ __launch_bounds__(256) void ballquery_kernel(
    const float* __restrict__ xyz, const float* __restrict__ new_xyz,
    int* __restrict__ idxo)
{
  const int c = blockIdx.x * 4 + (threadIdx.x >> 6);
  const int lane = threadIdx.x & 63;
  const int b = c >> 11;
  const float* __restrict__ xb = xyz + (size_t)b * 3 * N_;
  float cx = new_xyz[c * 3 + 0], cy = new_xyz[c * 3 + 1], cz = new_xyz[c * 3 + 2];
  float css = __fadd_rn(__fadd_rn(__fmul_rn(cx, cx), __fmul_rn(cy, cy)),
                        __fmul_rn(cz, cz));
  const double rr = 0.3 * 0.3;
  int cnt = 0, first = -1;
  for (int base = 0; base < N_; base += 64) {
    int j = base + lane;
    float x = xb[j], y = xb[N_ + j], z = xb[2 * N_ + j];
    float pss = __fadd_rn(__fadd_rn(__fmul_rn(x, x), __fmul_rn(y, y)),
                          __fmul_rn(z, z));
    float dot = __fadd_rn(__fadd_rn(__fmul_rn(cx, x), __fmul_rn(cy, y)),
                          __fmul_rn(cz, z));
    float d = __fadd_rn(__fadd_rn(__fmul_rn(-2.f, dot), css), pss);
    bool in = (double)d <= rr;
    unsigned long long m = __ballot(in);
    if (m) {
      if (first < 0) first = base + (__ffsll((long long)m) - 1);
      int rank = (int)__popcll(m & ((1ull << lane) - 1ull));
      int pos = cnt + rank;
      if (in && pos < K_) idxo[(size_t)c * K_ + pos] = j;
      cnt += (int)__popcll(m);
      if (cnt >= K_) break;
    }
  }
  for (int p = cnt + lane; p < K_; p += 64) idxo[(size_t)c * K_ + p] = first;
}

// ---------------------------------------------------------------------------
// points (B,D,N) -> (B,N,D) (only used when ws_size permits).
// ---------------------------------------------------------------------------
__global__ __launch_bounds__(256) void transpose_pts_kernel(
    const float* __restrict__ pts, float* __restrict__ pts_t)
{
  __shared__ float tile[64][65];
  const int blk = blockIdx.x;
  const int b = blk >> 8;
  const int n0 = (blk & 255) * 64;
  const int tx = threadIdx.x & 63, ty = threadIdx.x >> 6;
#pragma unroll
  for (int r = 0; r < 16; ++r) {
    int d = r * 4 + ty;
    tile[d][tx] = pts[((size_t)b * D_ + d) * N_ + n0 + tx];
  }
  __syncthreads();
#pragma unroll
  for (int r = 0; r < 16; ++r) {
    int nl = r * 4 + ty;
    pts_t[((size_t)b * N_ + n0 + nl) * D_ + tx] = tile[tx][nl];
  }
}

__global__ void transpose_w_kernel(
    const float* __restrict__ W0, const float* __restrict__ W1,
    const float* __restrict__ W2, float* __restrict__ wt0,
    float* __restrict__ wt1, float* __restrict__ wt2)
{
  int i = blockIdx.x * 256 + threadIdx.x;
  if (i < 128 * 67) { int co = i / 67, ci = i % 67; wt0[ci * 128 + co] = W0[i]; }
  int i1 = i - 128 * 67;
  if (i1 >= 0 && i1 < 128 * 128) { int co = i1 >> 7, ci = i1 & 127; wt1[ci * 128 + co] = W1[i1]; }
  int i2 = i1 - 128 * 128;
  if (i2 >= 0 && i2 < 256 * 128) { int co = i2 >> 7, ci = i2 & 127; wt2[ci * 256 + co] = W2[i2]; }
}

// ---------------------------------------------------------------------------
// Shared device helpers for the recompute passes.
// ---------------------------------------------------------------------------
__device__ __forceinline__ void stage_x0(
    int gp0, int tid, const float* __restrict__ xyz,
    const float* __restrict__ pts, const float* __restrict__ pts_t, int use_pt,
    const float* __restrict__ new_xyz, const int* __restrict__ idxo,
    float* __restrict__ bufA)
{
  int pxl = tid >> 2, q = tid & 3;
  int gp = gp0 + pxl;
  int b = gp >> 16;
  int s = (gp >> 5) & (S_ - 1);
  int j = idxo[gp];
  if (use_pt) {
    const float* src = pts_t + ((size_t)b * N_ + j) * 64 + q * 16;
#pragma unroll
    for (int v = 0; v < 4; ++v) {
      float4 f = *(const float4*)(src + v * 4);
      int c = 3 + q * 16 + v * 4;
      bufA[(c + 0) * 72 + pxl] = f.x;
      bufA[(c + 1) * 72 + pxl] = f.y;
      bufA[(c + 2) * 72 + pxl] = f.z;
      bufA[(c + 3) * 72 + pxl] = f.w;
    }
  } else {
    const float* src = pts + ((size_t)b * D_ + q * 16) * N_ + j;
#pragma unroll
    for (int v = 0; v < 16; ++v)
      bufA[(3 + q * 16 + v) * 72 + pxl] = src[(size_t)v * N_];
  }
  if (q == 0) {
    const float* xb = xyz + (size_t)b * 3 * N_;
    int c3 = (b * S_ + s) * 3;
    bufA[0 * 72 + pxl] = xb[j] - new_xyz[c3 + 0];
    bufA[1 * 72 + pxl] = xb[N_ + j] - new_xyz[c3 + 1];
    bufA[2 * 72 + pxl] = xb[2 * N_ + j] - new_xyz[c3 + 2];
  }
}

// 8-cout conv micro-tile: acc[4 px][8 co] += buf[ci][pg*4..] * w[ci][cog*8..]
template<int CIN>
__device__ __forceinline__ void conv8(
    const float* __restrict__ buf, const float* __restrict__ wrow, int pg,
    float acc[4][8])
{
  for (int ci = 0; ci < CIN; ++ci) {
    float4 x4 = *(const float4*)&buf[ci * 72 + pg * 4];
    float4 wa = *(const float4*)&wrow[ci * 128];
    float4 wb = *(const float4*)&wrow[ci * 128 + 4];
    float xr[4] = {x4.x, x4.y, x4.z, x4.w};
    float wv[8] = {wa.x, wa.y, wa.z, wa.w, wb.x, wb.y, wb.z, wb.w};
#pragma unroll
    for (int i = 0; i < 4; ++i)
#pragma unroll
      for (int j = 0; j < 8; ++j) acc[i][j] = fmaf(xr[i], wv[j], acc[i][j]);
  }
}

// ---------------------------------------------------------------------------
// passA: conv0 stats only (no y0 store).
// ---------------------------------------------------------------------------
__global__ __launch_bounds__(256) void passA_kernel(
    const float* __restrict__ xyz, const float* __restrict__ pts,
    const float* __restrict__ pts_t, int use_pt,
    const float* __restrict__ new_xyz, const int* __restrict__ idxo,
    const float* __restrict__ wt0, const float* __restrict__ b0,
    float* __restrict__ gsum, float* __restrict__ gsq)
{
  __shared__ __align__(16) float bufA[C0_ * 72];
  __shared__ float s_sum[4][128], s_sq[4][128];
  const int tid = threadIdx.x;
  const int lane = tid & 63, wid = tid >> 6;
  const int cog = tid & 15, pg = tid >> 4;
  float bias[8];
#pragma unroll
  for (int j = 0; j < 8; ++j) bias[j] = b0[cog * 8 + j];
  float ssum[8], ssq[8];
#pragma unroll
  for (int j = 0; j < 8; ++j) { ssum[j] = 0.f; ssq[j] = 0.f; }

  for (int t = 0; t < 4; ++t) {
    const int gp0 = (blockIdx.x * 4 + t) * 64;
    __syncthreads();
    stage_x0(gp0, tid, xyz, pts, pts_t, use_pt, new_xyz, idxo, bufA);
    __syncthreads();
    float acc[4][8];
#pragma unroll
    for (int i = 0; i < 4; ++i)
#pragma unroll
      for (int j = 0; j < 8; ++j) acc[i][j] = 0.f;
    conv8<C0_>(bufA, wt0 + cog * 8, pg, acc);
#pragma unroll
    for (int i = 0; i < 4; ++i)
#pragma unroll
      for (int j = 0; j < 8; ++j) {
        float y = acc[i][j] + bias[j];
        ssum[j] += y;
        ssq[j] = fmaf(y, y, ssq[j]);
      }
  }
#pragma unroll
  for (int j = 0; j < 8; ++j) {
    float v = ssum[j];
    v += __shfl_xor(v, 16, 64); v += __shfl_xor(v, 32, 64);
    float q = ssq[j];
    q += __shfl_xor(q, 16, 64); q += __shfl_xor(q, 32, 64);
    if (lane < 16) { s_sum[wid][lane * 8 + j] = v; s_sq[wid][lane * 8 + j] = q; }
  }
  __syncthreads();
  if (tid < 128) {
    float v = s_sum[0][tid] + s_sum[1][tid] + s_sum[2][tid] + s_sum[3][tid];
    float q = s_sq[0][tid] + s_sq[1][tid] + s_sq[2][tid] + s_sq[3][tid];
    atomicAdd(&gsum[tid], v);
    atomicAdd(&gsq[tid], q);
  }
}

// ---------------------------------------------------------------------------
// passB: recompute conv0 -> BN0+ReLU -> conv1 stats (no y1 store).
// ---------------------------------------------------------------------------
__global__ __launch_bounds__(256) void passB_kernel(
    const float* __restrict__ xyz, const float* __restrict__ pts,
    const float* __restrict__ pts_t, int use_pt,
    const float* __restrict__ new_xyz, const int* __restrict__ idxo,
    const float* __restrict__ wt0, const float* __restrict__ b0,
    const float* __restrict__ scale0, const float* __restrict__ shift0,
    const float* __restrict__ wt1, const float* __restrict__ b1,
    float* __restrict__ gsum, float* __restrict__ gsq)
{
  __shared__ __align__(16) float bufA[C0_ * 72];
  __shared__ __align__(16) float bufB[128 * 72];
  __shared__ float s_sum[4][128], s_sq[4][128];
  const int tid = threadIdx.x;
  const int lane = tid & 63, wid = tid >> 6;
  const int cog = tid & 15, pg = tid >> 4;
  float bias0[8], bias1[8], sc0[8], sh0[8];
#pragma unroll
  for (int j = 0; j < 8; ++j) {
    bias0[j] = b0[cog * 8 + j];
    bias1[j] = b1[cog * 8 + j];
    sc0[j] = scale0[cog * 8 + j];
    sh0[j] = shift0[cog * 8 + j];
  }
  float ssum[8], ssq[8];
#pragma unroll
  for (int j = 0; j < 8; ++j) { ssum[j] = 0.f; ssq[j] = 0.f; }

  for (int t = 0; t < 4; ++t) {
    const int gp0 = (blockIdx.x * 4 + t) * 64;
    __syncthreads();
    stage_x0(gp0, tid, xyz, pts, pts_t, use_pt, new_xyz, idxo, bufA);
    __syncthreads();
    float acc[4][8];
#pragma unroll
    for (int i = 0; i < 4; ++i)
#pragma unroll
      for (int j = 0; j < 8; ++j) acc[i][j] = 0.f;
    conv8<C0_>(bufA, wt0 + cog * 8, pg, acc);
#pragma unroll
    for (int i = 0; i < 4; ++i)
#pragma unroll
      for (int j = 0; j < 8; ++j) {
        float y = acc[i][j] + bias0[j];
        bufB[(cog * 8 + j) * 72 + pg * 4 + i] = fmaxf(0.f, fmaf(y, sc0[j], sh0[j]));
      }
    __syncthreads();
#pragma unroll
    for (int i = 0; i < 4; ++i)
#pragma unroll
      for (int j = 0; j < 8; ++j) acc[i][j] = 0.f;
    conv8<128>(bufB, wt1 + cog * 8, pg, acc);
#pragma unroll
    for (int i = 0; i < 4; ++i)
#pragma unroll
      for (int j = 0; j < 8; ++j) {
        float y = acc[i][j] + bias1[j];
        ssum[j] += y;
        ssq[j] = fmaf(y, y, ssq[j]);
      }
  }
#pragma unroll
  for (int j = 0; j < 8; ++j) {
    float v = ssum[j];
    v += __shfl_xor(v, 16, 64); v += __shfl_xor(v, 32, 64);
    float q = ssq[j];
    q += __shfl_xor(q, 16, 64); q += __shfl_xor(q, 32, 64);
    if (lane < 16) { s_sum[wid][lane * 8 + j] = v; s_sq[wid][lane * 8 + j] = q; }
  }
  __syncthreads();
  if (tid < 128) {
    float v = s_sum[0][tid] + s_sum[1][tid] + s_sum[2][tid] + s_sum[3][tid];
    float q = s_sq[0][tid] + s_sq[1][tid] + s_sq[2][tid] + s_sq[3][tid];
    atomicAdd(&gsum[tid], v);
    atomicAdd(&gsq[tid], q);
  }
}

// ---------------------------------------------------------------------------
// passC: recompute conv0->BN0->conv1->BN1->conv2; emit per-centroid max/min
// of y2 (BN2+ReLU is monotone affine) + conv2 stats. Never stores y2.
// ---------------------------------------------------------------------------
__global__ __launch_bounds__(256) void passC_kernel(
    const float* __restrict__ xyz, const float* __restrict__ pts,
    const float* __restrict__ pts_t, int use_pt,
    const float* __restrict__ new_xyz, const int* __restrict__ idxo,
    const float* __restrict__ wt0, const float* __restrict__ b0,
    const float* __restrict__ scale0, const float* __restrict__ shift0,
    const float* __restrict__ wt1, const float* __restrict__ b1,
    const float* __restrict__ scale1, const float* __restrict__ shift1,
    const float* __restrict__ wt2, const float* __restrict__ b2,
    float* __restrict__ m2max, float* __restrict__ m2min,
    float* __restrict__ gsum, float* __restrict__ gsq)
{
  __shared__ __align__(16) float bufA[128 * 72];   // x0 (67 rows) then x2 (128 rows)
  __shared__ __align__(16) float bufB[128 * 72];   // x1
  __shared__ float s_m[4 * 256], s_n[4 * 256];
  __shared__ float s_sum[4][256], s_sq[4][256];
  const int tid = threadIdx.x;
  const int lane = tid & 63, wid = tid >> 6;
  const int cog = tid & 15, pg = tid >> 4;
  const int co0 = cog * 16;
  float bias0[8], bias1[8], sc0[8], sh0[8], sc1[8], sh1[8];
#pragma unroll
  for (int j = 0; j < 8; ++j) {
    bias0[j] = b0[cog * 8 + j];
    bias1[j] = b1[cog * 8 + j];
    sc0[j] = scale0[cog * 8 + j];
    sh0[j] = shift0[cog * 8 + j];
    sc1[j] = scale1[cog * 8 + j];
    sh1[j] = shift1[cog * 8 + j];
  }
  float bias2[16];
#pragma unroll
  for (int j = 0; j < 16; ++j) bias2[j] = b2[co0 + j];
  float ssum[16], ssq[16];
#pragma unroll
  for (int j = 0; j < 16; ++j) { ssum[j] = 0.f; ssq[j] = 0.f; }

  for (int t = 0; t < 4; ++t) {
    const int gp0 = (blockIdx.x * 4 + t) * 64;
    __syncthreads();
    stage_x0(gp0, tid, xyz, pts, pts_t, use_pt, new_xyz, idxo, bufA);
    __syncthreads();
    // conv0 -> x1
    {
      float acc[4][8];
#pragma unroll
      for (int i = 0; i < 4; ++i)
#pragma unroll
        for (int j = 0; j < 8; ++j) acc[i][j] = 0.f;
      conv8<C0_>(bufA, wt0 + cog * 8, pg, acc);
#pragma unroll
      for (int i = 0; i < 4; ++i)
#pragma unroll
        for (int j = 0; j < 8; ++j) {
          float y = acc[i][j] + bias0[j];
          bufB[(cog * 8 + j) * 72 + pg * 4 + i] = fmaxf(0.f, fmaf(y, sc0[j], sh0[j]));
        }
    }
    __syncthreads();                 // all conv0 reads of bufA done
    // conv1 -> x2 (into bufA)
    {
      float acc[4][8];
#pragma unroll
      for (int i = 0; i < 4; ++i)
#pragma unroll
        for (int j = 0; j < 8; ++j) acc[i][j] = 0.f;
      conv8<128>(bufB, wt1 + cog * 8, pg, acc);
#pragma unroll
      for (int i = 0; i < 4; ++i)
#pragma unroll
        for (int j = 0; j < 8; ++j) {
          float y = acc[i][j] + bias1[j];
          bufA[(cog * 8 + j) * 72 + pg * 4 + i] = fmaxf(0.f, fmaf(y, sc1[j], sh1[j]));
        }
    }
    __syncthreads();
    // conv2 -> stats + per-centroid max/min
    {
      float acc[4][16];
#pragma unroll
      for (int i = 0; i < 4; ++i)
#pragma unroll
        for (int j = 0; j < 16; ++j) acc[i][j] = 0.f;
      const float* wrow = wt2 + co0;
      for (int ci = 0; ci < 128; ++ci) {
        float4 x4 = *(const float4*)&bufA[ci * 72 + pg * 4];
        float xr[4] = {x4.x, x4.y, x4.z, x4.w};
        float wv[16];
#pragma unroll
        for (int w4 = 0; w4 < 4; ++w4) {
          float4 wf = *(const float4*)&wrow[ci * 256 + w4 * 4];
          wv[w4 * 4 + 0] = wf.x; wv[w4 * 4 + 1] = wf.y;
          wv[w4 * 4 + 2] = wf.z; wv[w4 * 4 + 3] = wf.w;
        }
#pragma unroll
        for (int i = 0; i < 4; ++i)
#pragma unroll
          for (int j = 0; j < 16; ++j) acc[i][j] = fmaf(xr[i], wv[j], acc[i][j]);
      }
      float mx[16], mn[16];
#pragma unroll
      for (int j = 0; j < 16; ++j) { mx[j] = -3.4e38f; mn[j] = 3.4e38f; }
#pragma unroll
      for (int i = 0; i < 4; ++i)
#pragma unroll
        for (int j = 0; j < 16; ++j) {
          float y = acc[i][j] + bias2[j];
          ssum[j] += y;
          ssq[j] = fmaf(y, y, ssq[j]);
          mx[j] = fmaxf(mx[j], y);
          mn[j] = fminf(mn[j], y);
        }
#pragma unroll
      for (int j = 0; j < 16; ++j) {
        float a = mx[j];
        a = fmaxf(a, __shfl_xor(a, 16, 64)); a = fmaxf(a, __shfl_xor(a, 32, 64));
        float c = mn[j];
        c = fminf(c, __shfl_xor(c, 16, 64)); c = fminf(c, __shfl_xor(c, 32, 64));
        if (lane < 16) {
          s_m[wid * 256 + lane * 16 + j] = a;
          s_n[wid * 256 + lane * 16 + j] = c;
        }
      }
      __syncthreads();
      {
        int co = tid;
        size_t bsA = (size_t)(gp0 >> 5);   // global (b*S+s) of first centroid
        m2max[bsA * 256 + co]       = fmaxf(s_m[co], s_m[256 + co]);
        m2max[(bsA + 1) * 256 + co] = fmaxf(s_m[512 + co], s_m[768 + co]);
        m2min[bsA * 256 + co]       = fminf(s_n[co], s_n[256 + co]);
        m2min[(bsA + 1) * 256 + co] = fminf(s_n[512 + co], s_n[768 + co]);
      }
    }
  }
#pragma unroll
  for (int j = 0; j < 16; ++j) {
    float v = ssum[j];
    v += __shfl_xor(v, 16, 64); v += __shfl_xor(v, 32, 64);
    float q = ssq[j];
    q += __shfl_xor(q, 16, 64); q += __shfl_xor(q, 32, 64);
    if (lane < 16) { s_sum[wid][lane * 16 + j] = v; s_sq[wid][lane * 16 + j] = q; }
  }
  __syncthreads();
  {
    int co = tid;
    float v = s_sum[0][co] + s_sum[1][co] + s_sum[2][co] + s_sum[3][co];
    float q = s_sq[0][co] + s_sq[1][co] + s_sq[2][co] + s_sq[3][co];
    atomicAdd(&gsum[co], v);
    atomicAdd(&gsq[co], q);
  }
}

__global__ void stats_kernel(
    const float* __restrict__ gsum, const float* __restrict__ gsq,
    const float* __restrict__ g, const float* __restrict__ be,
    float* __restrict__ scale, float* __restrict__ shift, int C)
{
  int c = threadIdx.x;
  if (c >= C) return;
  const float invP = 1.0f / (float)P_;   // P = 2^18, exact division
  float mean = gsum[c] * invP;
  float var = fmaxf(gsq[c] * invP - mean * mean, 0.f);
  float r = 1.0f / sqrtf(var + 1e-5f);
  float sc = g[c] * r;
  scale[c] = sc;
  shift[c] = be[c] - mean * sc;
}

// feat[b][c][s] = relu(scale2*(scale2>=0 ? max : min) + shift2), transposed.
__global__ __launch_bounds__(256) void final_kernel(
    const float* __restrict__ m2max, const float* __restrict__ m2min,
    const float* __restrict__ scale2, const float* __restrict__ shift2,
    float* __restrict__ d_out)
{
  __shared__ float tmx[64][65], tmn[64][65];
  const int blk = blockIdx.x;
  const int b = blk >> 7;
  const int st = (blk >> 2) & 31;
  const int ct = blk & 3;
  const int s0 = st * 64, c0 = ct * 64;
  const int tx = threadIdx.x & 63, ty = threadIdx.x >> 6;
#pragma unroll
  for (int r = 0; r < 16; ++r) {
    int sl = r * 4 + ty;
    size_t src = ((size_t)(b * S_ + s0 + sl)) * 256 + c0 + tx;
    tmx[sl][tx] = m2max[src];
    tmn[sl][tx] = m2min[src];
  }
  __syncthreads();
#pragma unroll
  for (int r = 0; r < 16; ++r) {
    int cl = r * 4 + ty;
    int c = c0 + cl;
    float sc = scale2[c], sh = shift2[c];
    float m = (sc >= 0.f) ? tmx[tx][cl] : tmn[tx][cl];
    d_out[FEAT_OFF + ((size_t)(b * C3_ + c)) * S_ + s0 + tx] =
        fmaxf(0.f, fmaf(m, sc, sh));
  }
}

// ---------------------------------------------------------------------------
extern "C" void kernel_launch(void* const* d_in, const int* in_sizes, int n_in,
                              void* d_out_v, int out_size, void* d_ws,
                              size_t ws_size, hipStream_t stream)
{
  (void)in_sizes; (void)n_in; (void)out_size;
  const float* xyz = (const float*)d_in[0];
  const float* pts = (const float*)d_in[1];
  const int* seed = (const int*)d_in[2];
  const int* fstart = (const int*)d_in[3];
  const float* W0 = (const float*)d_in[4];
  const float* b0 = (const float*)d_in[5];
  const float* g0 = (const float*)d_in[6];
  const float* be0 = (const float*)d_in[7];
  const float* W1 = (const float*)d_in[8];
  const float* b1 = (const float*)d_in[9];
  const float* g1 = (const float*)d_in[10];
  const float* be1 = (const float*)d_in[11];
  const float* W2 = (const float*)d_in[12];
  const float* b2 = (const float*)d_in[13];
  const float* g2 = (const float*)d_in[14];
  const float* be2 = (const float*)d_in[15];
  float* out = (float*)d_out_v;
  char* ws = (char*)d_ws;

  size_t off = 0;
  auto alloc = [&](size_t bytes) -> void* {
    off = (off + 255) & ~(size_t)255;
    void* p = ws + off;
    off += bytes;
    return p;
  };
  // Compact layout: ~18 MB (+16 MB pts_t only if ws_size allows).
  int*   fps_idx = (int*)alloc((size_t)B_ * S_ * 4);
  float* new_xyz = (float*)alloc((size_t)B_ * S_ * 3 * 4);
  int*   idxo    = (int*)alloc((size_t)B_ * S_ * K_ * 4);
  float* m2max   = (float*)alloc((size_t)B_ * S_ * 256 * 4);
  float* m2min   = (float*)alloc((size_t)B_ * S_ * 256 * 4);
  float* stats   = (float*)alloc(1024 * 4);
  float* scsh    = (float*)alloc(1024 * 4);
  float* wt0     = (float*)alloc((size_t)67 * 128 * 4);
  float* wt1     = (float*)alloc((size_t)128 * 128 * 4);
  float* wt2     = (float*)alloc((size_t)128 * 256 * 4);
  const int use_pt = (ws_size >= (off + (size_t)B_ * N_ * D_ * 4 + (1u << 20))) ? 1 : 0;
  float* pts_t   = use_pt ? (float*)alloc((size_t)B_ * N_ * D_ * 4) : (float*)ws;

  float* gsum0 = stats, *gsq0 = stats + 128;
  float* gsum1 = stats + 256, *gsq1 = stats + 384;
  float* gsum2 = stats + 512, *gsq2 = stats + 768;
  float* scale0 = scsh, *shift0 = scsh + 128;
  float* scale1 = scsh + 256, *shift1 = scsh + 384;
  float* scale2 = scsh + 512, *shift2 = scsh + 768;

  hipMemsetAsync(stats, 0, 1024 * 4, stream);
  transpose_w_kernel<<<226, 256, 0, stream>>>(W0, W1, W2, wt0, wt1, wt2);
  if (use_pt)
    transpose_pts_kernel<<<B_ * 256, 256, 0, stream>>>(pts, pts_t);
  fps_kernel<<<B_, 512, 0, stream>>>(xyz, seed, fstart, fps_idx, new_xyz, out);
  ballquery_kernel<<<B_ * S_ / 4, 256, 0, stream>>>(xyz, new_xyz, idxo);
  passA_kernel<<<1024, 256, 0, stream>>>(xyz, pts, pts_t, use_pt, new_xyz, idxo,
                                         wt0, b0, gsum0, gsq0);
  stats_kernel<<<1, 128, 0, stream>>>(gsum0, gsq0, g0, be0, scale0, shift0, 128);
  passB_kernel<<<1024, 256, 0, stream>>>(xyz, pts, pts_t, use_pt, new_xyz, idxo,
                                         wt0, b0, scale0, shift0, wt1, b1,
                                         gsum1, gsq1);
  stats_kernel<<<1, 128, 0, stream>>>(gsum1, gsq1, g1, be1, scale1, shift1, 128);
  passC_kernel<<<1024, 256, 0, stream>>>(xyz, pts, pts_t, use_pt, new_xyz, idxo,
                                         wt0, b0, scale0, shift0, wt1, b1,
                                         scale1, shift1, wt2, b2,
                                         m2max, m2min, gsum2, gsq2);
  stats_kernel<<<1, 256, 0, stream>>>(gsum2, gsq2, g2, be2, scale2, shift2, 256);
  final_kernel<<<512, 256, 0, stream>>>(m2max, m2min, scale2, shift2, out);
}